// Round 1
// baseline (1732.924 us; speedup 1.0000x reference)
//
#include <hip/hip_runtime.h>
#include <cstdint>
#include <cmath>

// MMoE forward, MI355X. B=16384 L=200 SD=64 CONCAT=244 NE=8 EH=256 EO=128 NT=2.
// Strategy: bf16 MFMA (f32 accum) for attention MLP + experts; VALU for tail.
// Layer-1 folding: feat@aW1 = t@(A1+A3) + h@(A2-A3) + (t*h)@A4 ; ab3 cancels in softmax.

typedef __attribute__((ext_vector_type(8))) short bfrag;   // 8 x bf16 (A/B frag)
typedef __attribute__((ext_vector_type(4))) float f32x4;   // C/D frag

__device__ __forceinline__ unsigned short f2bf(float f) {
  union { float f; unsigned u; } v; v.f = f;
  unsigned r = v.u + 0x7FFFu + ((v.u >> 16) & 1u);
  return (unsigned short)(r >> 16);
}
__device__ __forceinline__ float bf2f(unsigned short b) {
  union { unsigned u; float f; } v; v.u = ((unsigned)b) << 16;
  return v.f;
}

#define SWZ(row, col) ((col) ^ (((row) & 7) << 3))   // element-unit XOR swizzle (16B chunks)

// ---------------- workspace layout (bytes) ----------------
static constexpr size_t WS_ATTNB = 0;                       // bf16 [64][128]  (n-major: [n][k])
static constexpr size_t WS_AW2T  = WS_ATTNB + 16384;        // bf16 [16][64]
static constexpr size_t WS_A13   = WS_AW2T + 2048;          // f32  [64][64]   ([k][n])
static constexpr size_t WS_EW1T  = WS_A13 + 16384;          // bf16 [8][256][256] ([e][n][k], k>=244 zero)
static constexpr size_t WS_EW2T  = WS_EW1T + 1048576;       // bf16 [8][128][256] ([e][n][k])
static constexpr size_t WS_HISTB = WS_EW2T + 524288;        // bf16 [100001][64]
static constexpr size_t WS_TGT   = WS_HISTB + 12800256;     // bf16 [B][64]
static constexpr size_t WS_TA    = WS_TGT + 2097152;        // f32  [B][64]
static constexpr size_t WS_SHP   = WS_TA + 4194304;         // bf16 [B][256] (padded shared)
static constexpr size_t WS_EO    = WS_SHP + 8388608;        // bf16 [B][8][128]
// total = WS_EO + 33554432 = 62,642,432 bytes (~60 MB) of d_ws

// ---------------- k0: fold/transpose/bf16-cast weights + hist table ----------------
__launch_bounds__(256)
__global__ void k0_prep(const float* __restrict__ aW1, const float* __restrict__ aW2,
                        const float* __restrict__ eW1, const float* __restrict__ eW2,
                        const float* __restrict__ hist_E,
                        unsigned short* __restrict__ attnBt, unsigned short* __restrict__ aW2t,
                        float* __restrict__ A13,
                        unsigned short* __restrict__ eW1t, unsigned short* __restrict__ eW2t,
                        unsigned short* __restrict__ hist_b) {
  int tid = blockIdx.x * blockDim.x + threadIdx.x;
  int nth = gridDim.x * blockDim.x;
  // attnBt[n][k]: k<64 -> A2-A3 (h part), k>=64 -> A4 (t*h part)
  for (int i = tid; i < 64 * 128; i += nth) {
    int n = i >> 7, k = i & 127;
    float v = (k < 64) ? (aW1[(64 + k) * 64 + n] - aW1[(128 + k) * 64 + n])
                       : aW1[(128 + k) * 64 + n];
    attnBt[i] = f2bf(v);
  }
  // A13[k][n] = A1 + A3 (f32, for exact tA)
  for (int i = tid; i < 64 * 64; i += nth) {
    int k = i >> 6, n = i & 63;
    A13[i] = aW1[k * 64 + n] + aW1[(128 + k) * 64 + n];
  }
  // aW2t[n][k]
  for (int i = tid; i < 16 * 64; i += nth) {
    int n = i >> 6, k = i & 63;
    aW2t[i] = f2bf(aW2[k * 16 + n]);
  }
  // eW1t[e][n][k] (k<244 valid else 0)
  for (int i = tid; i < 8 * 256 * 256; i += nth) {
    int e = i >> 16, n = (i >> 8) & 255, k = i & 255;
    eW1t[i] = (k < 244) ? f2bf(eW1[(e * 244 + k) * 256 + n]) : (unsigned short)0;
  }
  // eW2t[e][n][k]
  for (int i = tid; i < 8 * 128 * 256; i += nth) {
    int e = i >> 15, n = (i >> 8) & 127, k = i & 255;
    eW2t[i] = f2bf(eW2[(e * 256 + k) * 128 + n]);
  }
  // bf16 hist table (halves gather traffic in k2)
  for (int i = tid; i < 100001 * 64; i += nth) hist_b[i] = f2bf(hist_E[i]);
}

// ---------------- k1: t = i_emb @ Wproj ; tA = t @ (A1+A3) + ab1 ----------------
__launch_bounds__(256)
__global__ void k1_tgt(const int* __restrict__ item_id, const float* __restrict__ item_E,
                       const float* __restrict__ Wproj, const float* __restrict__ A13,
                       const float* __restrict__ ab1,
                       unsigned short* __restrict__ tgt, float* __restrict__ tA) {
  __shared__ float Wp[64 * 64], A13s[64 * 64], ab1s[64];
  __shared__ float ivb[4][64], tbuf[4][64];
  int tid = threadIdx.x, w = tid >> 6, lane = tid & 63;
  for (int i = tid; i < 4096; i += 256) { Wp[i] = Wproj[i]; A13s[i] = A13[i]; }
  if (tid < 64) ab1s[tid] = ab1[tid];
  __syncthreads();
  int b0 = blockIdx.x * 16;
  for (int it = 0; it < 4; ++it) {
    int b = b0 + w * 4 + it;
    int iid = item_id[b];
    ivb[w][lane] = item_E[(size_t)iid * 64 + lane];
    __syncthreads();
    float t = 0.f;
#pragma unroll 8
    for (int k = 0; k < 64; ++k) t += ivb[w][k] * Wp[k * 64 + lane];
    tbuf[w][lane] = t;
    __syncthreads();
    float ta = ab1s[lane];
#pragma unroll 8
    for (int k = 0; k < 64; ++k) ta += tbuf[w][k] * A13s[k * 64 + lane];
    tgt[(size_t)b * 64 + lane] = f2bf(t);
    tA[(size_t)b * 64 + lane] = ta;
  }
}

// ---------------- k3a: assemble shared (cols 0..179, pad 244..255) ----------------
__launch_bounds__(256)
__global__ void k3a_assemble(const int* __restrict__ user_id, const int* __restrict__ item_id,
                             const int* __restrict__ item_cat, const int* __restrict__ item_dur,
                             const float* __restrict__ user_dense, const float* __restrict__ item_dense,
                             const float* __restrict__ user_E, const float* __restrict__ item_E,
                             const float* __restrict__ cat_E, const float* __restrict__ dur_E,
                             unsigned short* __restrict__ shared_p) {
  int tid = threadIdx.x, w = tid >> 6, lane = tid & 63;
  int b = blockIdx.x * 4 + w;
  unsigned short* row = shared_p + (size_t)b * 256;
  row[lane]      = f2bf(user_E[(size_t)user_id[b] * 64 + lane]);
  row[64 + lane] = f2bf(item_E[(size_t)item_id[b] * 64 + lane]);
  if (lane < 16) row[128 + lane] = f2bf(cat_E[item_cat[b] * 16 + lane]);
  if (lane < 8)  row[144 + lane] = f2bf(dur_E[item_dur[b] * 8 + lane]);
  if (lane < 25) row[152 + lane] = f2bf(user_dense[b * 25 + lane]);
  if (lane < 3)  row[177 + lane] = f2bf(item_dense[b * 3 + lane]);
  if (lane < 12) row[244 + lane] = 0;
}

// ---------------- k2: fused DIN attention per batch element ----------------
__launch_bounds__(256, 1)
__global__ void k2_attn(const int* __restrict__ hist_seq, const unsigned short* __restrict__ hist_b,
                        const unsigned short* __restrict__ tgt, const float* __restrict__ tA,
                        const unsigned short* __restrict__ attnBt_g, const unsigned short* __restrict__ aW2t_g,
                        const float* __restrict__ ab2, const float* __restrict__ aW3,
                        unsigned short* __restrict__ shared_p) {
  __shared__ unsigned short sA[208 * 128];   // [l][0..63]=h bf16, [64..127]=t*h bf16 (swizzled)
  __shared__ unsigned short sBt[64 * 128];   // layer1 B, n-major (swizzled)
  __shared__ unsigned short sH1[208 * 64];   // layer1 output bf16 (swizzled)
  __shared__ unsigned short sW2[16 * 64];    // layer2 B, n-major (swizzled)
  __shared__ int   ids[208];
  __shared__ float tv[64], tAv[64];
  __shared__ float sSc[208];
  __shared__ float red[8];
  __shared__ float pbuf[256];
  int b = blockIdx.x;
  int tid = threadIdx.x, w = tid >> 6, lane = tid & 63;

  if (tid < 208) ids[tid] = (tid < 200) ? hist_seq[(size_t)b * 200 + tid] : 0;
  if (tid < 64) tv[tid] = bf2f(tgt[(size_t)b * 64 + tid]);
  else if (tid < 128) tAv[tid - 64] = tA[(size_t)b * 64 + (tid - 64)];
  for (int j = tid; j < 1024; j += 256) {         // sBt: 64 rows x 16 chunks
    int n = j >> 4, ke = (j & 15) * 8;
    uint4 v = *(const uint4*)(attnBt_g + n * 128 + ke);
    *(uint4*)(sBt + n * 128 + SWZ(n, ke)) = v;
  }
  if (tid < 128) {                                // sW2: 16 rows x 8 chunks
    int n = tid >> 3, ke = (tid & 7) * 8;
    uint4 v = *(const uint4*)(aW2t_g + n * 64 + ke);
    *(uint4*)(sW2 + n * 64 + SWZ(n, ke)) = v;
  }
  __syncthreads();

  // gather h (bf16 pairs) and compute t*h
  {
    int half = lane >> 5, hl = lane & 31;
    for (int i = 0; i < 52; ++i) {
      int l = w + 4 * i;
      unsigned hv = 0;
      if (l < 200) {
        int id = ids[l];
        hv = *(const unsigned*)(hist_b + (size_t)id * 64 + 2 * hl);
      }
      if (half == 0) {
        int col = 2 * hl;
        *(unsigned*)(sA + l * 128 + SWZ(l, col)) = hv;
      } else {
        float h0 = bf2f((unsigned short)(hv & 0xffff));
        float h1 = bf2f((unsigned short)(hv >> 16));
        unsigned pk = (unsigned)f2bf(h0 * tv[2 * hl]) | ((unsigned)f2bf(h1 * tv[2 * hl + 1]) << 16);
        int col = 64 + 2 * hl;
        *(unsigned*)(sA + l * 128 + SWZ(l, col)) = pk;
      }
    }
  }
  __syncthreads();

  // layer 1: (208x128) @ (128x64), MFMA 16x16x32
  int lr = lane & 15, g = lane >> 4;
  bfrag bfr[4][4];
#pragma unroll
  for (int nt = 0; nt < 4; ++nt)
#pragma unroll
    for (int kk = 0; kk < 4; ++kk) {
      int nn = nt * 16 + lr, k0 = kk * 32 + g * 8;
      bfr[nt][kk] = *(const bfrag*)(sBt + nn * 128 + SWZ(nn, k0));
    }
  for (int mt = w; mt < 13; mt += 4) {
    f32x4 acc[4] = {{0.f,0.f,0.f,0.f},{0.f,0.f,0.f,0.f},{0.f,0.f,0.f,0.f},{0.f,0.f,0.f,0.f}};
    int m = mt * 16 + lr;
    bfrag afr[4];
#pragma unroll
    for (int kk = 0; kk < 4; ++kk) {
      int k0 = kk * 32 + g * 8;
      afr[kk] = *(const bfrag*)(sA + m * 128 + SWZ(m, k0));
    }
#pragma unroll
    for (int kk = 0; kk < 4; ++kk)
#pragma unroll
      for (int nt = 0; nt < 4; ++nt)
        acc[nt] = __builtin_amdgcn_mfma_f32_16x16x32_bf16(afr[kk], bfr[nt][kk], acc[nt], 0, 0, 0);
#pragma unroll
    for (int nt = 0; nt < 4; ++nt) {
      int n = nt * 16 + lr;
      float ta = tAv[n];
#pragma unroll
      for (int r = 0; r < 4; ++r) {
        float v = fmaxf(acc[nt][r] + ta, 0.f);
        int mm = mt * 16 + g * 4 + r;
        sH1[mm * 64 + SWZ(mm, n)] = f2bf(v);
      }
    }
  }
  __syncthreads();

  // layer 2: (208x64)@(64x16), + layer 3 dot via shuffle
  bfrag b2fr[2];
#pragma unroll
  for (int kk = 0; kk < 2; ++kk) {
    int k0 = kk * 32 + g * 8;
    b2fr[kk] = *(const bfrag*)(sW2 + lr * 64 + SWZ(lr, k0));
  }
  float ab2v = ab2[lr];
  float aW3v = aW3[lr];
  for (int mt = w; mt < 13; mt += 4) {
    f32x4 acc = {0.f, 0.f, 0.f, 0.f};
    int m = mt * 16 + lr;
#pragma unroll
    for (int kk = 0; kk < 2; ++kk) {
      int k0 = kk * 32 + g * 8;
      bfrag a = *(const bfrag*)(sH1 + m * 64 + SWZ(m, k0));
      acc = __builtin_amdgcn_mfma_f32_16x16x32_bf16(a, b2fr[kk], acc, 0, 0, 0);
    }
    float sc[4];
#pragma unroll
    for (int r = 0; r < 4; ++r) sc[r] = fmaxf(acc[r] + ab2v, 0.f) * aW3v;
#pragma unroll
    for (int d = 1; d < 16; d <<= 1)
#pragma unroll
      for (int r = 0; r < 4; ++r) sc[r] += __shfl_xor(sc[r], d);
    if (lr == 0) {
      int mr = mt * 16 + g * 4;
      sSc[mr] = sc[0]; sSc[mr + 1] = sc[1]; sSc[mr + 2] = sc[2]; sSc[mr + 3] = sc[3];
    }
  }
  __syncthreads();

  // masked softmax + pooled
  bool valid = false; float sc0 = 0.f;
  if (tid < 200 && ids[tid] != 0) { valid = true; sc0 = sSc[tid]; }
  float v = valid ? sc0 : -3.0e38f;
#pragma unroll
  for (int d = 1; d < 64; d <<= 1) v = fmaxf(v, __shfl_xor(v, d));
  if (lane == 0) red[w] = v;
  __syncthreads();
  float mx = fmaxf(fmaxf(red[0], red[1]), fmaxf(red[2], red[3]));
  float p = valid ? expf(sc0 - mx) : 0.f;
  float s = p;
#pragma unroll
  for (int d = 1; d < 64; d <<= 1) s += __shfl_xor(s, d);
  if (lane == 0) red[4 + w] = s;
  if (tid < 208) sSc[tid] = p;
  __syncthreads();
  float denom = red[4] + red[5] + red[6] + red[7] + 1e-30f;
  int d0 = tid & 63, ch = tid >> 6;
  float acc = 0.f;
  for (int i = 0; i < 52; ++i) {
    int l = ch * 52 + i;
    acc += sSc[l] * bf2f(sA[l * 128 + SWZ(l, d0)]);
  }
  pbuf[ch * 64 + d0] = acc;
  __syncthreads();
  if (tid < 64) {
    float tot = pbuf[tid] + pbuf[64 + tid] + pbuf[128 + tid] + pbuf[192 + tid];
    shared_p[(size_t)b * 256 + 180 + tid] = f2bf(tot / denom);
  }
}

// ---------------- k3b: experts (64-row tile x one expert per block) ----------------
__launch_bounds__(256, 2)
__global__ void k3b_experts(const unsigned short* __restrict__ shared_p,
                            const unsigned short* __restrict__ eW1t, const unsigned short* __restrict__ eW2t,
                            const float* __restrict__ eb1, const float* __restrict__ eb2,
                            unsigned short* __restrict__ eo_ws) {
  __shared__ unsigned short sX[64 * 256];   // X tile then reused as H1 tile (swizzled)
  __shared__ unsigned short sW[256 * 64];   // weight K-chunk, n-major (swizzled)
  int tid = threadIdx.x, w = tid >> 6, lane = tid & 63;
  int e = blockIdx.x & 7;
  int b0 = (blockIdx.x >> 3) * 64;
  int lr = lane & 15, g = lane >> 4;

  for (int j = tid; j < 2048; j += 256) {
    int r = j >> 5, ke = (j & 31) * 8;
    uint4 v = *(const uint4*)(shared_p + (size_t)(b0 + r) * 256 + ke);
    *(uint4*)(sX + r * 256 + SWZ(r, ke)) = v;
  }
  f32x4 acc[16];
#pragma unroll
  for (int i = 0; i < 16; ++i) acc[i] = (f32x4){0.f, 0.f, 0.f, 0.f};
  const unsigned short* w1 = eW1t + (size_t)e * 256 * 256;
  for (int c = 0; c < 4; ++c) {
    __syncthreads();
    for (int j = tid; j < 2048; j += 256) {
      int n = j >> 3, ke = (j & 7) * 8;
      uint4 v = *(const uint4*)(w1 + n * 256 + c * 64 + ke);
      *(uint4*)(sW + n * 64 + SWZ(n, ke)) = v;
    }
    __syncthreads();
    int m = w * 16 + lr;
#pragma unroll
    for (int kk = 0; kk < 2; ++kk) {
      int kabs = c * 64 + kk * 32 + g * 8;
      bfrag a = *(const bfrag*)(sX + m * 256 + SWZ(m, kabs));
      int kloc = kk * 32 + g * 8;
#pragma unroll
      for (int nt = 0; nt < 16; ++nt) {
        int n = nt * 16 + lr;
        bfrag bb = *(const bfrag*)(sW + n * 64 + SWZ(n, kloc));
        acc[nt] = __builtin_amdgcn_mfma_f32_16x16x32_bf16(a, bb, acc[nt], 0, 0, 0);
      }
    }
  }
  __syncthreads();
  // h1 = relu(acc + eb1) -> reuse sX
#pragma unroll
  for (int nt = 0; nt < 16; ++nt) {
    int n = nt * 16 + lr;
    float bb = eb1[e * 256 + n];
#pragma unroll
    for (int r = 0; r < 4; ++r) {
      float vv = fmaxf(acc[nt][r] + bb, 0.f);
      int mm = w * 16 + g * 4 + r;
      sX[mm * 256 + SWZ(mm, n)] = f2bf(vv);
    }
  }
  f32x4 acc2[8];
#pragma unroll
  for (int i = 0; i < 8; ++i) acc2[i] = (f32x4){0.f, 0.f, 0.f, 0.f};
  const unsigned short* w2 = eW2t + (size_t)e * 128 * 256;
  for (int c = 0; c < 4; ++c) {
    __syncthreads();
    for (int j = tid; j < 1024; j += 256) {
      int n = j >> 3, ke = (j & 7) * 8;
      uint4 v = *(const uint4*)(w2 + n * 256 + c * 64 + ke);
      *(uint4*)(sW + n * 64 + SWZ(n, ke)) = v;
    }
    __syncthreads();
    int m = w * 16 + lr;
#pragma unroll
    for (int kk = 0; kk < 2; ++kk) {
      int kabs = c * 64 + kk * 32 + g * 8;
      bfrag a = *(const bfrag*)(sX + m * 256 + SWZ(m, kabs));
      int kloc = kk * 32 + g * 8;
#pragma unroll
      for (int nt = 0; nt < 8; ++nt) {
        int n = nt * 16 + lr;
        bfrag bb = *(const bfrag*)(sW + n * 64 + SWZ(n, kloc));
        acc2[nt] = __builtin_amdgcn_mfma_f32_16x16x32_bf16(a, bb, acc2[nt], 0, 0, 0);
      }
    }
  }
#pragma unroll
  for (int nt = 0; nt < 8; ++nt) {
    int n = nt * 16 + lr;
    float bb = eb2[e * 128 + n];
#pragma unroll
    for (int r = 0; r < 4; ++r) {
      float vv = fmaxf(acc2[nt][r] + bb, 0.f);
      int mm = w * 16 + g * 4 + r;
      eo_ws[((size_t)(b0 + mm) * 8 + e) * 128 + n] = f2bf(vv);
    }
  }
}

// ---------------- k4: gates + mixture + towers + sigmoid ----------------
__launch_bounds__(256, 1)
__global__ void k4_tail(const unsigned short* __restrict__ shared_p, const unsigned short* __restrict__ eo_ws,
                        const float* __restrict__ gW, const float* __restrict__ gb,
                        const float* __restrict__ tW1, const float* __restrict__ tb1,
                        const float* __restrict__ tW2, const float* __restrict__ tb2,
                        const float* __restrict__ tW3, const float* __restrict__ tb3,
                        float* __restrict__ out) {
  __shared__ float gWt[2 * 8 * 256];     // [t][e][c] (c padded to 256)
  __shared__ float sT1[2 * 128 * 64];
  __shared__ float sT2[2 * 64 * 32];
  __shared__ float sT3[64], sB1[128], sB2[64], sB3[2], sGb[16];
  __shared__ float tiBuf[4][2][128];
  __shared__ float x1Buf[4][2][64];
  int tid = threadIdx.x, w = tid >> 6, lane = tid & 63;
  for (int i = tid; i < 2 * 8 * 256; i += 256) {
    int t = i >> 11, e = (i >> 8) & 7, c = i & 255;
    gWt[i] = (c < 244) ? gW[(t * 244 + c) * 8 + e] : 0.f;
  }
  for (int i = tid; i < 2 * 128 * 64; i += 256) sT1[i] = tW1[i];
  for (int i = tid; i < 2 * 64 * 32; i += 256) sT2[i] = tW2[i];
  if (tid < 64) sT3[tid] = tW3[tid];
  if (tid < 128) sB1[tid] = tb1[tid];
  if (tid < 64) sB2[tid] = tb2[tid];
  if (tid < 2) sB3[tid] = tb3[tid];
  if (tid < 16) sGb[tid] = gb[tid];
  __syncthreads();
  int b0 = blockIdx.x * 32;
  for (int it = 0; it < 8; ++it) {
    int b = b0 + it * 4 + w;
    const unsigned short* srow = shared_p + (size_t)b * 256;
    float s0 = bf2f(srow[lane]), s1 = bf2f(srow[64 + lane]);
    float s2 = bf2f(srow[128 + lane]), s3 = bf2f(srow[192 + lane]);
    float part[16];
#pragma unroll
    for (int te = 0; te < 16; ++te) {
      const float* gr = gWt + te * 256;
      part[te] = s0 * gr[lane] + s1 * gr[64 + lane] + s2 * gr[128 + lane] + s3 * gr[192 + lane];
    }
#pragma unroll
    for (int d = 1; d < 64; d <<= 1)
#pragma unroll
      for (int te = 0; te < 16; ++te) part[te] += __shfl_xor(part[te], d);
    float gate[16];
#pragma unroll
    for (int t = 0; t < 2; ++t) {
      float mxv = -3e38f;
#pragma unroll
      for (int e = 0; e < 8; ++e) mxv = fmaxf(mxv, part[t * 8 + e] + sGb[t * 8 + e]);
      float sum = 0.f;
#pragma unroll
      for (int e = 0; e < 8; ++e) {
        float pe = expf(part[t * 8 + e] + sGb[t * 8 + e] - mxv);
        gate[t * 8 + e] = pe; sum += pe;
      }
      float inv = 1.f / sum;
#pragma unroll
      for (int e = 0; e < 8; ++e) gate[t * 8 + e] *= inv;
    }
    float ti0a = 0.f, ti0b = 0.f, ti1a = 0.f, ti1b = 0.f;
    const unsigned short* eor = eo_ws + (size_t)b * 1024;
#pragma unroll
    for (int e = 0; e < 8; ++e) {
      float ea = bf2f(eor[e * 128 + lane]);
      float eb = bf2f(eor[e * 128 + 64 + lane]);
      ti0a += gate[e] * ea;     ti0b += gate[e] * eb;
      ti1a += gate[8 + e] * ea; ti1b += gate[8 + e] * eb;
    }
    tiBuf[w][0][lane] = ti0a; tiBuf[w][0][64 + lane] = ti0b;
    tiBuf[w][1][lane] = ti1a; tiBuf[w][1][64 + lane] = ti1b;
    __syncthreads();
#pragma unroll
    for (int t = 0; t < 2; ++t) {
      float x = sB1[t * 64 + lane];
      const float* wt = sT1 + t * 8192;
      const float* tb = tiBuf[w][t];
#pragma unroll 4
      for (int k = 0; k < 128; ++k) x += tb[k] * wt[k * 64 + lane];
      x1Buf[w][t][lane] = fmaxf(x, 0.f);
    }
    __syncthreads();
    {
      int t = lane >> 5, j2 = lane & 31;
      float x = sB2[t * 32 + j2];
      const float* wt = sT2 + t * 2048;
      const float* xb = x1Buf[w][t];
#pragma unroll 4
      for (int k = 0; k < 64; ++k) x += xb[k] * wt[k * 32 + j2];
      x = fmaxf(x, 0.f);
      float pr = x * sT3[t * 32 + j2];
#pragma unroll
      for (int d = 1; d < 32; d <<= 1) pr += __shfl_xor(pr, d);
      if (j2 == 0) {
        float logit = pr + sB3[t];
        out[(size_t)t * 16384 + b] = 1.f / (1.f + expf(-logit));
      }
    }
    __syncthreads();
  }
}

// ---------------- launcher ----------------
extern "C" void kernel_launch(void* const* d_in, const int* in_sizes, int n_in,
                              void* d_out, int out_size, void* d_ws, size_t ws_size,
                              hipStream_t stream) {
  const int*   user_id    = (const int*)  d_in[0];
  const int*   item_id    = (const int*)  d_in[1];
  const int*   item_cat   = (const int*)  d_in[2];
  const int*   item_dur   = (const int*)  d_in[3];
  const float* user_dense = (const float*)d_in[4];
  const float* item_dense = (const float*)d_in[5];
  const int*   hist_seq   = (const int*)  d_in[6];
  const float* user_E     = (const float*)d_in[7];
  const float* item_E     = (const float*)d_in[8];
  const float* cat_E      = (const float*)d_in[9];
  const float* dur_E      = (const float*)d_in[10];
  const float* hist_E     = (const float*)d_in[11];
  const float* Wproj      = (const float*)d_in[12];
  const float* aW1        = (const float*)d_in[13];
  const float* ab1        = (const float*)d_in[14];
  const float* aW2        = (const float*)d_in[15];
  const float* ab2        = (const float*)d_in[16];
  const float* aW3        = (const float*)d_in[17];
  // d_in[18] = ab3: cancels in softmax, unused
  const float* eW1        = (const float*)d_in[19];
  const float* eb1        = (const float*)d_in[20];
  const float* eW2        = (const float*)d_in[21];
  const float* eb2        = (const float*)d_in[22];
  const float* gW         = (const float*)d_in[23];
  const float* gb         = (const float*)d_in[24];
  const float* tW1        = (const float*)d_in[25];
  const float* tb1        = (const float*)d_in[26];
  const float* tW2        = (const float*)d_in[27];
  const float* tb2        = (const float*)d_in[28];
  const float* tW3        = (const float*)d_in[29];
  const float* tb3        = (const float*)d_in[30];
  float* out = (float*)d_out;
  char* ws = (char*)d_ws;

  unsigned short* attnBt  = (unsigned short*)(ws + WS_ATTNB);
  unsigned short* aW2t    = (unsigned short*)(ws + WS_AW2T);
  float*          A13     = (float*)         (ws + WS_A13);
  unsigned short* eW1t    = (unsigned short*)(ws + WS_EW1T);
  unsigned short* eW2t    = (unsigned short*)(ws + WS_EW2T);
  unsigned short* hist_b  = (unsigned short*)(ws + WS_HISTB);
  unsigned short* tgt     = (unsigned short*)(ws + WS_TGT);
  float*          tA      = (float*)         (ws + WS_TA);
  unsigned short* shared_p= (unsigned short*)(ws + WS_SHP);
  unsigned short* eo_ws   = (unsigned short*)(ws + WS_EO);

  k0_prep<<<2048, 256, 0, stream>>>(aW1, aW2, eW1, eW2, hist_E,
                                    attnBt, aW2t, A13, eW1t, eW2t, hist_b);
  k1_tgt<<<1024, 256, 0, stream>>>(item_id, item_E, Wproj, A13, ab1, tgt, tA);
  k3a_assemble<<<4096, 256, 0, stream>>>(user_id, item_id, item_cat, item_dur,
                                         user_dense, item_dense, user_E, item_E,
                                         cat_E, dur_E, shared_p);
  k2_attn<<<16384, 256, 0, stream>>>(hist_seq, hist_b, tgt, tA, attnBt, aW2t,
                                     ab2, aW3, shared_p);
  k3b_experts<<<2048, 256, 0, stream>>>(shared_p, eW1t, eW2t, eb1, eb2, eo_ws);
  k4_tail<<<512, 256, 0, stream>>>(shared_p, eo_ws, gW, gb, tW1, tb1, tW2, tb2,
                                   tW3, tb3, out);
}

// Round 2
// 508.896 us; speedup vs baseline: 3.4053x; 3.4053x over previous
//
#include <hip/hip_runtime.h>
#include <cstdint>
#include <cmath>

// MMoE forward, MI355X. B=16384 L=200 SD=64 CONCAT=244 NE=8 EH=256 EO=128 NT=2.
// Strategy: bf16 MFMA (f32 accum) for attention MLP + experts; VALU for tail.
// Layer-1 folding: feat@aW1 = t@(A1+A3) + h@(A2-A3) + (t*h)@A4 ; ab3 cancels in softmax.
// R2: k2 rebuilt for occupancy — A/B fragments straight from global, LDS only for H1.

typedef __attribute__((ext_vector_type(8))) short bfrag;   // 8 x bf16 (A/B frag)
typedef __attribute__((ext_vector_type(4))) float f32x4;   // C/D frag

__device__ __forceinline__ unsigned short f2bf(float f) {
  union { float f; unsigned u; } v; v.f = f;
  unsigned r = v.u + 0x7FFFu + ((v.u >> 16) & 1u);
  return (unsigned short)(r >> 16);
}
__device__ __forceinline__ float bf2f(unsigned short b) {
  union { unsigned u; float f; } v; v.u = ((unsigned)b) << 16;
  return v.f;
}

#define SWZ(row, col) ((col) ^ (((row) & 7) << 3))   // element-unit XOR swizzle (16B chunks)

// ---------------- workspace layout (bytes) ----------------
static constexpr size_t WS_ATTNB = 0;                       // bf16 [64][128]  (n-major: [n][k])
static constexpr size_t WS_AW2T  = WS_ATTNB + 16384;        // bf16 [16][64]
static constexpr size_t WS_A13   = WS_AW2T + 2048;          // f32  [64][64]   ([k][n])
static constexpr size_t WS_EW1T  = WS_A13 + 16384;          // bf16 [8][256][256] ([e][n][k], k>=244 zero)
static constexpr size_t WS_EW2T  = WS_EW1T + 1048576;       // bf16 [8][128][256] ([e][n][k])
static constexpr size_t WS_HISTB = WS_EW2T + 524288;        // bf16 [100001][64]
static constexpr size_t WS_TGT   = WS_HISTB + 12800256;     // bf16 [B][64]
static constexpr size_t WS_TA    = WS_TGT + 2097152;        // f32  [B][64]
static constexpr size_t WS_SHP   = WS_TA + 4194304;         // bf16 [B][256] (padded shared)
static constexpr size_t WS_EO    = WS_SHP + 8388608;        // bf16 [B][8][128]
// total = WS_EO + 33554432 = 62,642,432 bytes (~60 MB) of d_ws

// ---------------- k0: fold/transpose/bf16-cast weights + hist table ----------------
__launch_bounds__(256)
__global__ void k0_prep(const float* __restrict__ aW1, const float* __restrict__ aW2,
                        const float* __restrict__ eW1, const float* __restrict__ eW2,
                        const float* __restrict__ hist_E,
                        unsigned short* __restrict__ attnBt, unsigned short* __restrict__ aW2t,
                        float* __restrict__ A13,
                        unsigned short* __restrict__ eW1t, unsigned short* __restrict__ eW2t,
                        unsigned short* __restrict__ hist_b) {
  int tid = blockIdx.x * blockDim.x + threadIdx.x;
  int nth = gridDim.x * blockDim.x;
  // attnBt[n][k]: k<64 -> A2-A3 (h part), k>=64 -> A4 (t*h part)
  for (int i = tid; i < 64 * 128; i += nth) {
    int n = i >> 7, k = i & 127;
    float v = (k < 64) ? (aW1[(64 + k) * 64 + n] - aW1[(128 + k) * 64 + n])
                       : aW1[(128 + k) * 64 + n];
    attnBt[i] = f2bf(v);
  }
  // A13[k][n] = A1 + A3 (f32, for exact tA)
  for (int i = tid; i < 64 * 64; i += nth) {
    int k = i >> 6, n = i & 63;
    A13[i] = aW1[k * 64 + n] + aW1[(128 + k) * 64 + n];
  }
  // aW2t[n][k]
  for (int i = tid; i < 16 * 64; i += nth) {
    int n = i >> 6, k = i & 63;
    aW2t[i] = f2bf(aW2[k * 16 + n]);
  }
  // eW1t[e][n][k] (k<244 valid else 0)
  for (int i = tid; i < 8 * 256 * 256; i += nth) {
    int e = i >> 16, n = (i >> 8) & 255, k = i & 255;
    eW1t[i] = (k < 244) ? f2bf(eW1[(e * 244 + k) * 256 + n]) : (unsigned short)0;
  }
  // eW2t[e][n][k]
  for (int i = tid; i < 8 * 128 * 256; i += nth) {
    int e = i >> 15, n = (i >> 8) & 127, k = i & 255;
    eW2t[i] = f2bf(eW2[(e * 256 + k) * 128 + n]);
  }
  // bf16 hist table (halves gather traffic in k2)
  for (int i = tid; i < 100001 * 64; i += nth) hist_b[i] = f2bf(hist_E[i]);
}

// ---------------- k1: t = i_emb @ Wproj ; tA = t @ (A1+A3) + ab1 ----------------
__launch_bounds__(256)
__global__ void k1_tgt(const int* __restrict__ item_id, const float* __restrict__ item_E,
                       const float* __restrict__ Wproj, const float* __restrict__ A13,
                       const float* __restrict__ ab1,
                       unsigned short* __restrict__ tgt, float* __restrict__ tA) {
  __shared__ float Wp[64 * 64], A13s[64 * 64], ab1s[64];
  __shared__ float ivb[4][64], tbuf[4][64];
  int tid = threadIdx.x, w = tid >> 6, lane = tid & 63;
  for (int i = tid; i < 4096; i += 256) { Wp[i] = Wproj[i]; A13s[i] = A13[i]; }
  if (tid < 64) ab1s[tid] = ab1[tid];
  __syncthreads();
  int b0 = blockIdx.x * 16;
  for (int it = 0; it < 4; ++it) {
    int b = b0 + w * 4 + it;
    int iid = item_id[b];
    ivb[w][lane] = item_E[(size_t)iid * 64 + lane];
    __syncthreads();
    float t = 0.f;
#pragma unroll 8
    for (int k = 0; k < 64; ++k) t += ivb[w][k] * Wp[k * 64 + lane];
    tbuf[w][lane] = t;
    __syncthreads();
    float ta = ab1s[lane];
#pragma unroll 8
    for (int k = 0; k < 64; ++k) ta += tbuf[w][k] * A13s[k * 64 + lane];
    tgt[(size_t)b * 64 + lane] = f2bf(t);
    tA[(size_t)b * 64 + lane] = ta;
  }
}

// ---------------- k3a: assemble shared (cols 0..179, pad 244..255) ----------------
__launch_bounds__(256)
__global__ void k3a_assemble(const int* __restrict__ user_id, const int* __restrict__ item_id,
                             const int* __restrict__ item_cat, const int* __restrict__ item_dur,
                             const float* __restrict__ user_dense, const float* __restrict__ item_dense,
                             const float* __restrict__ user_E, const float* __restrict__ item_E,
                             const float* __restrict__ cat_E, const float* __restrict__ dur_E,
                             unsigned short* __restrict__ shared_p) {
  int tid = threadIdx.x, w = tid >> 6, lane = tid & 63;
  int b = blockIdx.x * 4 + w;
  unsigned short* row = shared_p + (size_t)b * 256;
  row[lane]      = f2bf(user_E[(size_t)user_id[b] * 64 + lane]);
  row[64 + lane] = f2bf(item_E[(size_t)item_id[b] * 64 + lane]);
  if (lane < 16) row[128 + lane] = f2bf(cat_E[item_cat[b] * 16 + lane]);
  if (lane < 8)  row[144 + lane] = f2bf(dur_E[item_dur[b] * 8 + lane]);
  if (lane < 25) row[152 + lane] = f2bf(user_dense[b * 25 + lane]);
  if (lane < 3)  row[177 + lane] = f2bf(item_dense[b * 3 + lane]);
  if (lane < 12) row[244 + lane] = 0;
}

// ---------------- k2: fused DIN attention per batch element (low-LDS, reg fragments) ----------------
__launch_bounds__(256, 3)
__global__ void k2_attn(const int* __restrict__ hist_seq, const unsigned short* __restrict__ hist_b,
                        const unsigned short* __restrict__ tgt, const float* __restrict__ tA,
                        const unsigned short* __restrict__ attnBt_g, const unsigned short* __restrict__ aW2t_g,
                        const float* __restrict__ ab2, const float* __restrict__ aW3,
                        unsigned short* __restrict__ shared_p) {
  __shared__ unsigned short sH1[208 * 64];   // layer1 output bf16 (swizzled)
  __shared__ int   ids[208];
  __shared__ float tv[64], tAv[64];
  __shared__ float sSc[208];
  __shared__ float red[8];
  __shared__ float pbuf[256];
  int b = blockIdx.x;
  int tid = threadIdx.x, w = tid >> 6, lane = tid & 63;
  int lr = lane & 15, g = lane >> 4;

  if (tid < 208) ids[tid] = (tid < 200) ? hist_seq[(size_t)b * 200 + tid] : 0;
  if (tid < 64) tv[tid] = bf2f(tgt[(size_t)b * 64 + tid]);
  else if (tid < 128) tAv[tid - 64] = tA[(size_t)b * 64 + (tid - 64)];

  // B fragments straight from global (L2-resident weights)
  bfrag bfr[4][4];
#pragma unroll
  for (int nt = 0; nt < 4; ++nt)
#pragma unroll
    for (int kk = 0; kk < 4; ++kk)
      bfr[nt][kk] = *(const bfrag*)(attnBt_g + (nt * 16 + lr) * 128 + kk * 32 + g * 8);
  bfrag b2fr[2];
#pragma unroll
  for (int kk = 0; kk < 2; ++kk)
    b2fr[kk] = *(const bfrag*)(aW2t_g + lr * 64 + kk * 32 + g * 8);
  float ab2v = ab2[lr];
  float aW3v = aW3[lr];
  __syncthreads();

  // per-lane t values for the t*h fragments (k-chunks g*8.. and 32+g*8..)
  float tk0[8], tk1[8];
#pragma unroll
  for (int i = 0; i < 8; ++i) { tk0[i] = tv[g * 8 + i]; tk1[i] = tv[32 + g * 8 + i]; }

  // layer 1: (208x128) @ (128x64); A gathered straight from global
  for (int mt = w; mt < 13; mt += 4) {
    int m = mt * 16 + lr;
    const unsigned short* hrow = hist_b + (size_t)ids[m] * 64;
    bfrag h0 = *(const bfrag*)(hrow + g * 8);          // k in [0,32) chunk
    bfrag h1 = *(const bfrag*)(hrow + 32 + g * 8);     // k in [32,64) chunk
    bfrag th0, th1;
#pragma unroll
    for (int i = 0; i < 8; ++i) {
      th0[i] = (short)f2bf(bf2f((unsigned short)h0[i]) * tk0[i]);
      th1[i] = (short)f2bf(bf2f((unsigned short)h1[i]) * tk1[i]);
    }
    f32x4 acc[4] = {{0.f,0.f,0.f,0.f},{0.f,0.f,0.f,0.f},{0.f,0.f,0.f,0.f},{0.f,0.f,0.f,0.f}};
#pragma unroll
    for (int nt = 0; nt < 4; ++nt) {
      acc[nt] = __builtin_amdgcn_mfma_f32_16x16x32_bf16(h0,  bfr[nt][0], acc[nt], 0, 0, 0);
      acc[nt] = __builtin_amdgcn_mfma_f32_16x16x32_bf16(h1,  bfr[nt][1], acc[nt], 0, 0, 0);
      acc[nt] = __builtin_amdgcn_mfma_f32_16x16x32_bf16(th0, bfr[nt][2], acc[nt], 0, 0, 0);
      acc[nt] = __builtin_amdgcn_mfma_f32_16x16x32_bf16(th1, bfr[nt][3], acc[nt], 0, 0, 0);
    }
#pragma unroll
    for (int nt = 0; nt < 4; ++nt) {
      int n = nt * 16 + lr;
      float ta = tAv[n];
#pragma unroll
      for (int r = 0; r < 4; ++r) {
        float v = fmaxf(acc[nt][r] + ta, 0.f);
        int mm = mt * 16 + g * 4 + r;
        sH1[mm * 64 + SWZ(mm, n)] = f2bf(v);
      }
    }
  }
  __syncthreads();

  // layer 2: (208x64)@(64x16), + layer 3 dot via shuffle
  for (int mt = w; mt < 13; mt += 4) {
    f32x4 acc = {0.f, 0.f, 0.f, 0.f};
    int m = mt * 16 + lr;
#pragma unroll
    for (int kk = 0; kk < 2; ++kk) {
      int k0 = kk * 32 + g * 8;
      bfrag a = *(const bfrag*)(sH1 + m * 64 + SWZ(m, k0));
      acc = __builtin_amdgcn_mfma_f32_16x16x32_bf16(a, b2fr[kk], acc, 0, 0, 0);
    }
    float sc[4];
#pragma unroll
    for (int r = 0; r < 4; ++r) sc[r] = fmaxf(acc[r] + ab2v, 0.f) * aW3v;
#pragma unroll
    for (int d = 1; d < 16; d <<= 1)
#pragma unroll
      for (int r = 0; r < 4; ++r) sc[r] += __shfl_xor(sc[r], d);
    if (lr == 0) {
      int mr = mt * 16 + g * 4;
      sSc[mr] = sc[0]; sSc[mr + 1] = sc[1]; sSc[mr + 2] = sc[2]; sSc[mr + 3] = sc[3];
    }
  }
  __syncthreads();

  // masked softmax
  bool valid = false; float sc0 = 0.f;
  if (tid < 200 && ids[tid] != 0) { valid = true; sc0 = sSc[tid]; }
  float v = valid ? sc0 : -3.0e38f;
#pragma unroll
  for (int d = 1; d < 64; d <<= 1) v = fmaxf(v, __shfl_xor(v, d));
  if (lane == 0) red[w] = v;
  __syncthreads();
  float mx = fmaxf(fmaxf(red[0], red[1]), fmaxf(red[2], red[3]));
  float p = valid ? expf(sc0 - mx) : 0.f;
  float s = p;
#pragma unroll
  for (int d = 1; d < 64; d <<= 1) s += __shfl_xor(s, d);
  if (lane == 0) red[4 + w] = s;
  if (tid < 208) sSc[tid] = p;
  __syncthreads();
  float denom = red[4] + red[5] + red[6] + red[7] + 1e-30f;

  // pooled: re-gather h (L2-warm) weighted by attn; wave w handles rows [w*50, w*50+50)
  float acc = 0.f;
  for (int i = 0; i < 50; ++i) {
    int l = w * 50 + i;
    float pw = sSc[l];
    acc += pw * bf2f(hist_b[(size_t)ids[l] * 64 + lane]);
  }
  pbuf[w * 64 + lane] = acc;
  __syncthreads();
  if (tid < 64) {
    float tot = pbuf[tid] + pbuf[64 + tid] + pbuf[128 + tid] + pbuf[192 + tid];
    shared_p[(size_t)b * 256 + 180 + tid] = f2bf(tot / denom);
  }
}

// ---------------- k3b: experts (64-row tile x one expert per block) ----------------
__launch_bounds__(256, 2)
__global__ void k3b_experts(const unsigned short* __restrict__ shared_p,
                            const unsigned short* __restrict__ eW1t, const unsigned short* __restrict__ eW2t,
                            const float* __restrict__ eb1, const float* __restrict__ eb2,
                            unsigned short* __restrict__ eo_ws) {
  __shared__ unsigned short sX[64 * 256];   // X tile then reused as H1 tile (swizzled)
  __shared__ unsigned short sW[256 * 64];   // weight K-chunk, n-major (swizzled)
  int tid = threadIdx.x, w = tid >> 6, lane = tid & 63;
  int e = blockIdx.x & 7;
  int b0 = (blockIdx.x >> 3) * 64;
  int lr = lane & 15, g = lane >> 4;

  for (int j = tid; j < 2048; j += 256) {
    int r = j >> 5, ke = (j & 31) * 8;
    uint4 v = *(const uint4*)(shared_p + (size_t)(b0 + r) * 256 + ke);
    *(uint4*)(sX + r * 256 + SWZ(r, ke)) = v;
  }
  f32x4 acc[16];
#pragma unroll
  for (int i = 0; i < 16; ++i) acc[i] = (f32x4){0.f, 0.f, 0.f, 0.f};
  const unsigned short* w1 = eW1t + (size_t)e * 256 * 256;
  for (int c = 0; c < 4; ++c) {
    __syncthreads();
    for (int j = tid; j < 2048; j += 256) {
      int n = j >> 3, ke = (j & 7) * 8;
      uint4 v = *(const uint4*)(w1 + n * 256 + c * 64 + ke);
      *(uint4*)(sW + n * 64 + SWZ(n, ke)) = v;
    }
    __syncthreads();
    int m = w * 16 + lr;
#pragma unroll
    for (int kk = 0; kk < 2; ++kk) {
      int kabs = c * 64 + kk * 32 + g * 8;
      bfrag a = *(const bfrag*)(sX + m * 256 + SWZ(m, kabs));
      int kloc = kk * 32 + g * 8;
#pragma unroll
      for (int nt = 0; nt < 16; ++nt) {
        int n = nt * 16 + lr;
        bfrag bb = *(const bfrag*)(sW + n * 64 + SWZ(n, kloc));
        acc[nt] = __builtin_amdgcn_mfma_f32_16x16x32_bf16(a, bb, acc[nt], 0, 0, 0);
      }
    }
  }
  __syncthreads();
  // h1 = relu(acc + eb1) -> reuse sX
#pragma unroll
  for (int nt = 0; nt < 16; ++nt) {
    int n = nt * 16 + lr;
    float bb = eb1[e * 256 + n];
#pragma unroll
    for (int r = 0; r < 4; ++r) {
      float vv = fmaxf(acc[nt][r] + bb, 0.f);
      int mm = w * 16 + g * 4 + r;
      sX[mm * 256 + SWZ(mm, n)] = f2bf(vv);
    }
  }
  f32x4 acc2[8];
#pragma unroll
  for (int i = 0; i < 8; ++i) acc2[i] = (f32x4){0.f, 0.f, 0.f, 0.f};
  const unsigned short* w2 = eW2t + (size_t)e * 128 * 256;
  for (int c = 0; c < 4; ++c) {
    __syncthreads();
    for (int j = tid; j < 1024; j += 256) {
      int n = j >> 3, ke = (j & 7) * 8;
      uint4 v = *(const uint4*)(w2 + n * 256 + c * 64 + ke);
      *(uint4*)(sW + n * 64 + SWZ(n, ke)) = v;
    }
    __syncthreads();
    int m = w * 16 + lr;
#pragma unroll
    for (int kk = 0; kk < 2; ++kk) {
      int kabs = c * 64 + kk * 32 + g * 8;
      bfrag a = *(const bfrag*)(sX + m * 256 + SWZ(m, kabs));
      int kloc = kk * 32 + g * 8;
#pragma unroll
      for (int nt = 0; nt < 8; ++nt) {
        int n = nt * 16 + lr;
        bfrag bb = *(const bfrag*)(sW + n * 64 + SWZ(n, kloc));
        acc2[nt] = __builtin_amdgcn_mfma_f32_16x16x32_bf16(a, bb, acc2[nt], 0, 0, 0);
      }
    }
  }
#pragma unroll
  for (int nt = 0; nt < 8; ++nt) {
    int n = nt * 16 + lr;
    float bb = eb2[e * 128 + n];
#pragma unroll
    for (int r = 0; r < 4; ++r) {
      float vv = fmaxf(acc2[nt][r] + bb, 0.f);
      int mm = w * 16 + g * 4 + r;
      eo_ws[((size_t)(b0 + mm) * 8 + e) * 128 + n] = f2bf(vv);
    }
  }
}

// ---------------- k4: gates + mixture + towers + sigmoid ----------------
__launch_bounds__(256, 1)
__global__ void k4_tail(const unsigned short* __restrict__ shared_p, const unsigned short* __restrict__ eo_ws,
                        const float* __restrict__ gW, const float* __restrict__ gb,
                        const float* __restrict__ tW1, const float* __restrict__ tb1,
                        const float* __restrict__ tW2, const float* __restrict__ tb2,
                        const float* __restrict__ tW3, const float* __restrict__ tb3,
                        float* __restrict__ out) {
  __shared__ float gWt[2 * 8 * 256];     // [t][e][c] (c padded to 256)
  __shared__ float sT1[2 * 128 * 64];
  __shared__ float sT2[2 * 64 * 32];
  __shared__ float sT3[64], sB1[128], sB2[64], sB3[2], sGb[16];
  __shared__ float tiBuf[4][2][128];
  __shared__ float x1Buf[4][2][64];
  int tid = threadIdx.x, w = tid >> 6, lane = tid & 63;
  for (int i = tid; i < 2 * 8 * 256; i += 256) {
    int t = i >> 11, e = (i >> 8) & 7, c = i & 255;
    gWt[i] = (c < 244) ? gW[(t * 244 + c) * 8 + e] : 0.f;
  }
  for (int i = tid; i < 2 * 128 * 64; i += 256) sT1[i] = tW1[i];
  for (int i = tid; i < 2 * 64 * 32; i += 256) sT2[i] = tW2[i];
  if (tid < 64) sT3[tid] = tW3[tid];
  if (tid < 128) sB1[tid] = tb1[tid];
  if (tid < 64) sB2[tid] = tb2[tid];
  if (tid < 2) sB3[tid] = tb3[tid];
  if (tid < 16) sGb[tid] = gb[tid];
  __syncthreads();
  int b0 = blockIdx.x * 32;
  for (int it = 0; it < 8; ++it) {
    int b = b0 + it * 4 + w;
    const unsigned short* srow = shared_p + (size_t)b * 256;
    float s0 = bf2f(srow[lane]), s1 = bf2f(srow[64 + lane]);
    float s2 = bf2f(srow[128 + lane]), s3 = bf2f(srow[192 + lane]);
    float part[16];
#pragma unroll
    for (int te = 0; te < 16; ++te) {
      const float* gr = gWt + te * 256;
      part[te] = s0 * gr[lane] + s1 * gr[64 + lane] + s2 * gr[128 + lane] + s3 * gr[192 + lane];
    }
#pragma unroll
    for (int d = 1; d < 64; d <<= 1)
#pragma unroll
      for (int te = 0; te < 16; ++te) part[te] += __shfl_xor(part[te], d);
    float gate[16];
#pragma unroll
    for (int t = 0; t < 2; ++t) {
      float mxv = -3e38f;
#pragma unroll
      for (int e = 0; e < 8; ++e) mxv = fmaxf(mxv, part[t * 8 + e] + sGb[t * 8 + e]);
      float sum = 0.f;
#pragma unroll
      for (int e = 0; e < 8; ++e) {
        float pe = expf(part[t * 8 + e] + sGb[t * 8 + e] - mxv);
        gate[t * 8 + e] = pe; sum += pe;
      }
      float inv = 1.f / sum;
#pragma unroll
      for (int e = 0; e < 8; ++e) gate[t * 8 + e] *= inv;
    }
    float ti0a = 0.f, ti0b = 0.f, ti1a = 0.f, ti1b = 0.f;
    const unsigned short* eor = eo_ws + (size_t)b * 1024;
#pragma unroll
    for (int e = 0; e < 8; ++e) {
      float ea = bf2f(eor[e * 128 + lane]);
      float eb = bf2f(eor[e * 128 + 64 + lane]);
      ti0a += gate[e] * ea;     ti0b += gate[e] * eb;
      ti1a += gate[8 + e] * ea; ti1b += gate[8 + e] * eb;
    }
    tiBuf[w][0][lane] = ti0a; tiBuf[w][0][64 + lane] = ti0b;
    tiBuf[w][1][lane] = ti1a; tiBuf[w][1][64 + lane] = ti1b;
    __syncthreads();
#pragma unroll
    for (int t = 0; t < 2; ++t) {
      float x = sB1[t * 64 + lane];
      const float* wt = sT1 + t * 8192;
      const float* tb = tiBuf[w][t];
#pragma unroll 4
      for (int k = 0; k < 128; ++k) x += tb[k] * wt[k * 64 + lane];
      x1Buf[w][t][lane] = fmaxf(x, 0.f);
    }
    __syncthreads();
    {
      int t = lane >> 5, j2 = lane & 31;
      float x = sB2[t * 32 + j2];
      const float* wt = sT2 + t * 2048;
      const float* xb = x1Buf[w][t];
#pragma unroll 4
      for (int k = 0; k < 64; ++k) x += xb[k] * wt[k * 32 + j2];
      x = fmaxf(x, 0.f);
      float pr = x * sT3[t * 32 + j2];
#pragma unroll
      for (int d = 1; d < 32; d <<= 1) pr += __shfl_xor(pr, d);
      if (j2 == 0) {
        float logit = pr + sB3[t];
        out[(size_t)t * 16384 + b] = 1.f / (1.f + expf(-logit));
      }
    }
    __syncthreads();
  }
}

// ---------------- launcher ----------------
extern "C" void kernel_launch(void* const* d_in, const int* in_sizes, int n_in,
                              void* d_out, int out_size, void* d_ws, size_t ws_size,
                              hipStream_t stream) {
  const int*   user_id    = (const int*)  d_in[0];
  const int*   item_id    = (const int*)  d_in[1];
  const int*   item_cat   = (const int*)  d_in[2];
  const int*   item_dur   = (const int*)  d_in[3];
  const float* user_dense = (const float*)d_in[4];
  const float* item_dense = (const float*)d_in[5];
  const int*   hist_seq   = (const int*)  d_in[6];
  const float* user_E     = (const float*)d_in[7];
  const float* item_E     = (const float*)d_in[8];
  const float* cat_E      = (const float*)d_in[9];
  const float* dur_E      = (const float*)d_in[10];
  const float* hist_E     = (const float*)d_in[11];
  const float* Wproj      = (const float*)d_in[12];
  const float* aW1        = (const float*)d_in[13];
  const float* ab1        = (const float*)d_in[14];
  const float* aW2        = (const float*)d_in[15];
  const float* ab2        = (const float*)d_in[16];
  const float* aW3        = (const float*)d_in[17];
  // d_in[18] = ab3: cancels in softmax, unused
  const float* eW1        = (const float*)d_in[19];
  const float* eb1        = (const float*)d_in[20];
  const float* eW2        = (const float*)d_in[21];
  const float* eb2        = (const float*)d_in[22];
  const float* gW         = (const float*)d_in[23];
  const float* gb         = (const float*)d_in[24];
  const float* tW1        = (const float*)d_in[25];
  const float* tb1        = (const float*)d_in[26];
  const float* tW2        = (const float*)d_in[27];
  const float* tb2        = (const float*)d_in[28];
  const float* tW3        = (const float*)d_in[29];
  const float* tb3        = (const float*)d_in[30];
  float* out = (float*)d_out;
  char* ws = (char*)d_ws;

  unsigned short* attnBt  = (unsigned short*)(ws + WS_ATTNB);
  unsigned short* aW2t    = (unsigned short*)(ws + WS_AW2T);
  float*          A13     = (float*)         (ws + WS_A13);
  unsigned short* eW1t    = (unsigned short*)(ws + WS_EW1T);
  unsigned short* eW2t    = (unsigned short*)(ws + WS_EW2T);
  unsigned short* hist_b  = (unsigned short*)(ws + WS_HISTB);
  unsigned short* tgt     = (unsigned short*)(ws + WS_TGT);
  float*          tA      = (float*)         (ws + WS_TA);
  unsigned short* shared_p= (unsigned short*)(ws + WS_SHP);
  unsigned short* eo_ws   = (unsigned short*)(ws + WS_EO);

  k0_prep<<<2048, 256, 0, stream>>>(aW1, aW2, eW1, eW2, hist_E,
                                    attnBt, aW2t, A13, eW1t, eW2t, hist_b);
  k1_tgt<<<1024, 256, 0, stream>>>(item_id, item_E, Wproj, A13, ab1, tgt, tA);
  k3a_assemble<<<4096, 256, 0, stream>>>(user_id, item_id, item_cat, item_dur,
                                         user_dense, item_dense, user_E, item_E,
                                         cat_E, dur_E, shared_p);
  k2_attn<<<16384, 256, 0, stream>>>(hist_seq, hist_b, tgt, tA, attnBt, aW2t,
                                     ab2, aW3, shared_p);
  k3b_experts<<<2048, 256, 0, stream>>>(shared_p, eW1t, eW2t, eb1, eb2, eo_ws);
  k4_tail<<<512, 256, 0, stream>>>(shared_p, eo_ws, gW, gb, tW1, tb1, tW2, tb2,
                                   tW3, tb3, out);
}

// Round 3
// 400.354 us; speedup vs baseline: 4.3285x; 1.2711x over previous
//
#include <hip/hip_runtime.h>
#include <cstdint>
#include <cmath>

// MMoE forward, MI355X. B=16384 L=200 SD=64 CONCAT=244 NE=8 EH=256 EO=128 NT=2.
// Strategy: bf16 MFMA (f32 accum) for attention MLP + experts; VALU for tail.
// Layer-1 folding: feat@aW1 = t@(A1+A3) + h@(A2-A3) + (t*h)@A4 ; ab3 cancels in softmax.
// R2: k2 rebuilt for occupancy — A/B fragments straight from global, LDS only for H1.
// R3: per-batch M-fold  M[n][k] = (A2-A3)[n][k] + t[k]*A4[n][k]  computed cooperatively
//     (kills t*h repack, halves layer-1 MFMA); launch_bounds(256,5); u32 pooling.

typedef __attribute__((ext_vector_type(8))) short bfrag;   // 8 x bf16 (A/B frag)
typedef __attribute__((ext_vector_type(4))) float f32x4;   // C/D frag

__device__ __forceinline__ unsigned short f2bf(float f) {
  union { float f; unsigned u; } v; v.f = f;
  unsigned r = v.u + 0x7FFFu + ((v.u >> 16) & 1u);
  return (unsigned short)(r >> 16);
}
__device__ __forceinline__ float bf2f(unsigned short b) {
  union { unsigned u; float f; } v; v.u = ((unsigned)b) << 16;
  return v.f;
}

#define SWZ(row, col) ((col) ^ (((row) & 7) << 3))   // element-unit XOR swizzle (16B chunks)

// ---------------- workspace layout (bytes) ----------------
static constexpr size_t WS_ATTNB = 0;                       // bf16 [64][128]  (n-major: [n][k])
static constexpr size_t WS_AW2T  = WS_ATTNB + 16384;        // bf16 [16][64]
static constexpr size_t WS_A13   = WS_AW2T + 2048;          // f32  [64][64]   ([k][n])
static constexpr size_t WS_EW1T  = WS_A13 + 16384;          // bf16 [8][256][256] ([e][n][k], k>=244 zero)
static constexpr size_t WS_EW2T  = WS_EW1T + 1048576;       // bf16 [8][128][256] ([e][n][k])
static constexpr size_t WS_HISTB = WS_EW2T + 524288;        // bf16 [100001][64]
static constexpr size_t WS_TGT   = WS_HISTB + 12800256;     // bf16 [B][64]
static constexpr size_t WS_TA    = WS_TGT + 2097152;        // f32  [B][64]
static constexpr size_t WS_SHP   = WS_TA + 4194304;         // bf16 [B][256] (padded shared)
static constexpr size_t WS_EO    = WS_SHP + 8388608;        // bf16 [B][8][128]
// total = WS_EO + 33554432 = 62,642,432 bytes (~60 MB) of d_ws

// ---------------- k0: fold/transpose/bf16-cast weights + hist table ----------------
__launch_bounds__(256)
__global__ void k0_prep(const float* __restrict__ aW1, const float* __restrict__ aW2,
                        const float* __restrict__ eW1, const float* __restrict__ eW2,
                        const float* __restrict__ hist_E,
                        unsigned short* __restrict__ attnBt, unsigned short* __restrict__ aW2t,
                        float* __restrict__ A13,
                        unsigned short* __restrict__ eW1t, unsigned short* __restrict__ eW2t,
                        unsigned short* __restrict__ hist_b) {
  int tid = blockIdx.x * blockDim.x + threadIdx.x;
  int nth = gridDim.x * blockDim.x;
  // attnBt[n][k]: k<64 -> A2-A3 (h part), k>=64 -> A4 (t*h part)
  for (int i = tid; i < 64 * 128; i += nth) {
    int n = i >> 7, k = i & 127;
    float v = (k < 64) ? (aW1[(64 + k) * 64 + n] - aW1[(128 + k) * 64 + n])
                       : aW1[(128 + k) * 64 + n];
    attnBt[i] = f2bf(v);
  }
  // A13[k][n] = A1 + A3 (f32, for exact tA)
  for (int i = tid; i < 64 * 64; i += nth) {
    int k = i >> 6, n = i & 63;
    A13[i] = aW1[k * 64 + n] + aW1[(128 + k) * 64 + n];
  }
  // aW2t[n][k]
  for (int i = tid; i < 16 * 64; i += nth) {
    int n = i >> 6, k = i & 63;
    aW2t[i] = f2bf(aW2[k * 16 + n]);
  }
  // eW1t[e][n][k] (k<244 valid else 0)
  for (int i = tid; i < 8 * 256 * 256; i += nth) {
    int e = i >> 16, n = (i >> 8) & 255, k = i & 255;
    eW1t[i] = (k < 244) ? f2bf(eW1[(e * 244 + k) * 256 + n]) : (unsigned short)0;
  }
  // eW2t[e][n][k]
  for (int i = tid; i < 8 * 128 * 256; i += nth) {
    int e = i >> 15, n = (i >> 8) & 127, k = i & 255;
    eW2t[i] = f2bf(eW2[(e * 256 + k) * 128 + n]);
  }
  // bf16 hist table (halves gather traffic in k2)
  for (int i = tid; i < 100001 * 64; i += nth) hist_b[i] = f2bf(hist_E[i]);
}

// ---------------- k1: t = i_emb @ Wproj ; tA = t @ (A1+A3) + ab1 ----------------
__launch_bounds__(256)
__global__ void k1_tgt(const int* __restrict__ item_id, const float* __restrict__ item_E,
                       const float* __restrict__ Wproj, const float* __restrict__ A13,
                       const float* __restrict__ ab1,
                       unsigned short* __restrict__ tgt, float* __restrict__ tA) {
  __shared__ float Wp[64 * 64], A13s[64 * 64], ab1s[64];
  __shared__ float ivb[4][64], tbuf[4][64];
  int tid = threadIdx.x, w = tid >> 6, lane = tid & 63;
  for (int i = tid; i < 4096; i += 256) { Wp[i] = Wproj[i]; A13s[i] = A13[i]; }
  if (tid < 64) ab1s[tid] = ab1[tid];
  __syncthreads();
  int b0 = blockIdx.x * 16;
  for (int it = 0; it < 4; ++it) {
    int b = b0 + w * 4 + it;
    int iid = item_id[b];
    ivb[w][lane] = item_E[(size_t)iid * 64 + lane];
    __syncthreads();
    float t = 0.f;
#pragma unroll 8
    for (int k = 0; k < 64; ++k) t += ivb[w][k] * Wp[k * 64 + lane];
    tbuf[w][lane] = t;
    __syncthreads();
    float ta = ab1s[lane];
#pragma unroll 8
    for (int k = 0; k < 64; ++k) ta += tbuf[w][k] * A13s[k * 64 + lane];
    tgt[(size_t)b * 64 + lane] = f2bf(t);
    tA[(size_t)b * 64 + lane] = ta;
  }
}

// ---------------- k3a: assemble shared (cols 0..179, pad 244..255) ----------------
__launch_bounds__(256)
__global__ void k3a_assemble(const int* __restrict__ user_id, const int* __restrict__ item_id,
                             const int* __restrict__ item_cat, const int* __restrict__ item_dur,
                             const float* __restrict__ user_dense, const float* __restrict__ item_dense,
                             const float* __restrict__ user_E, const float* __restrict__ item_E,
                             const float* __restrict__ cat_E, const float* __restrict__ dur_E,
                             unsigned short* __restrict__ shared_p) {
  int tid = threadIdx.x, w = tid >> 6, lane = tid & 63;
  int b = blockIdx.x * 4 + w;
  unsigned short* row = shared_p + (size_t)b * 256;
  row[lane]      = f2bf(user_E[(size_t)user_id[b] * 64 + lane]);
  row[64 + lane] = f2bf(item_E[(size_t)item_id[b] * 64 + lane]);
  if (lane < 16) row[128 + lane] = f2bf(cat_E[item_cat[b] * 16 + lane]);
  if (lane < 8)  row[144 + lane] = f2bf(dur_E[item_dur[b] * 8 + lane]);
  if (lane < 25) row[152 + lane] = f2bf(user_dense[b * 25 + lane]);
  if (lane < 3)  row[177 + lane] = f2bf(item_dense[b * 3 + lane]);
  if (lane < 12) row[244 + lane] = 0;
}

// ---------------- k2: fused DIN attention per batch element (M-fold, high occupancy) ----------------
__launch_bounds__(256, 5)
__global__ void k2_attn(const int* __restrict__ hist_seq, const unsigned short* __restrict__ hist_b,
                        const unsigned short* __restrict__ tgt, const float* __restrict__ tA,
                        const unsigned short* __restrict__ attnBt_g, const unsigned short* __restrict__ aW2t_g,
                        const float* __restrict__ ab2, const float* __restrict__ aW3,
                        unsigned short* __restrict__ shared_p) {
  __shared__ unsigned short sH1[208 * 64];   // layer1 output bf16 (swizzled); first 4096 transiently hold M
  __shared__ int   ids[208];
  __shared__ float tv[64], tAv[64];
  __shared__ float sSc[208];
  __shared__ float red[8];
  __shared__ float pbuf[512];
  int b = blockIdx.x;
  int tid = threadIdx.x, w = tid >> 6, lane = tid & 63;
  int lr = lane & 15, g = lane >> 4;

  if (tid < 208) ids[tid] = (tid < 200) ? hist_seq[(size_t)b * 200 + tid] : 0;
  if (tid < 64) tv[tid] = bf2f(tgt[(size_t)b * 64 + tid]);
  else if (tid < 128) tAv[tid - 64] = tA[(size_t)b * 64 + (tid - 64)];

  // layer-2 B fragments straight from global (L2-resident)
  bfrag b2fr[2];
#pragma unroll
  for (int kk = 0; kk < 2; ++kk)
    b2fr[kk] = *(const bfrag*)(aW2t_g + lr * 64 + kk * 32 + g * 8);
  float ab2v = ab2[lr];
  float aW3v = aW3[lr];
  __syncthreads();   // tv ready

  // cooperative M[n][k] = A23[n][k] + t[k]*A4[n][k]  into sH1[0:4096] (row stride 64, swizzled)
  {
    int n = tid >> 2, k0 = (tid & 3) * 16;
    const unsigned short* rowp = attnBt_g + n * 128;
    unsigned short a23[16], a4[16], mo[16];
    *(uint4*)(a23)     = *(const uint4*)(rowp + k0);
    *(uint4*)(a23 + 8) = *(const uint4*)(rowp + k0 + 8);
    *(uint4*)(a4)      = *(const uint4*)(rowp + 64 + k0);
    *(uint4*)(a4 + 8)  = *(const uint4*)(rowp + 64 + k0 + 8);
#pragma unroll
    for (int i = 0; i < 16; ++i)
      mo[i] = f2bf(bf2f(a23[i]) + tv[k0 + i] * bf2f(a4[i]));
    *(uint4*)(sH1 + n * 64 + SWZ(n, k0))     = *(uint4*)(mo);
    *(uint4*)(sH1 + n * 64 + SWZ(n, k0 + 8)) = *(uint4*)(mo + 8);
  }
  __syncthreads();   // M ready
  bfrag bfr[4][2];
#pragma unroll
  for (int nt = 0; nt < 4; ++nt)
#pragma unroll
    for (int kk = 0; kk < 2; ++kk) {
      int n = nt * 16 + lr;
      bfr[nt][kk] = *(const bfrag*)(sH1 + n * 64 + SWZ(n, kk * 32 + g * 8));
    }
  __syncthreads();   // all waves have M in regs; sH1 free for layer-1 output

  // layer 1: (208x64) @ (64x64) with per-batch folded M
  for (int mt = w; mt < 13; mt += 4) {
    int m = mt * 16 + lr;
    const unsigned short* hrow = hist_b + (size_t)ids[m] * 64;
    bfrag h0 = *(const bfrag*)(hrow + g * 8);          // k in [0,32)
    bfrag h1 = *(const bfrag*)(hrow + 32 + g * 8);     // k in [32,64)
    f32x4 acc[4] = {{0.f,0.f,0.f,0.f},{0.f,0.f,0.f,0.f},{0.f,0.f,0.f,0.f},{0.f,0.f,0.f,0.f}};
#pragma unroll
    for (int nt = 0; nt < 4; ++nt) {
      acc[nt] = __builtin_amdgcn_mfma_f32_16x16x32_bf16(h0, bfr[nt][0], acc[nt], 0, 0, 0);
      acc[nt] = __builtin_amdgcn_mfma_f32_16x16x32_bf16(h1, bfr[nt][1], acc[nt], 0, 0, 0);
    }
#pragma unroll
    for (int nt = 0; nt < 4; ++nt) {
      int n = nt * 16 + lr;
      float ta = tAv[n];
#pragma unroll
      for (int r = 0; r < 4; ++r) {
        float v = fmaxf(acc[nt][r] + ta, 0.f);
        int mm = mt * 16 + g * 4 + r;
        sH1[mm * 64 + SWZ(mm, n)] = f2bf(v);
      }
    }
  }
  __syncthreads();

  // layer 2: (208x64)@(64x16), + layer 3 dot via shuffle
  for (int mt = w; mt < 13; mt += 4) {
    f32x4 acc = {0.f, 0.f, 0.f, 0.f};
    int m = mt * 16 + lr;
#pragma unroll
    for (int kk = 0; kk < 2; ++kk) {
      int k0 = kk * 32 + g * 8;
      bfrag a = *(const bfrag*)(sH1 + m * 64 + SWZ(m, k0));
      acc = __builtin_amdgcn_mfma_f32_16x16x32_bf16(a, b2fr[kk], acc, 0, 0, 0);
    }
    float sc[4];
#pragma unroll
    for (int r = 0; r < 4; ++r) sc[r] = fmaxf(acc[r] + ab2v, 0.f) * aW3v;
#pragma unroll
    for (int d = 1; d < 16; d <<= 1)
#pragma unroll
      for (int r = 0; r < 4; ++r) sc[r] += __shfl_xor(sc[r], d);
    if (lr == 0) {
      int mr = mt * 16 + g * 4;
      sSc[mr] = sc[0]; sSc[mr + 1] = sc[1]; sSc[mr + 2] = sc[2]; sSc[mr + 3] = sc[3];
    }
  }
  __syncthreads();

  // masked softmax
  bool valid = false; float sc0 = 0.f;
  if (tid < 200 && ids[tid] != 0) { valid = true; sc0 = sSc[tid]; }
  float v = valid ? sc0 : -3.0e38f;
#pragma unroll
  for (int d = 1; d < 64; d <<= 1) v = fmaxf(v, __shfl_xor(v, d));
  if (lane == 0) red[w] = v;
  __syncthreads();
  float mx = fmaxf(fmaxf(red[0], red[1]), fmaxf(red[2], red[3]));
  float p = valid ? expf(sc0 - mx) : 0.f;
  float s = p;
#pragma unroll
  for (int d = 1; d < 64; d <<= 1) s += __shfl_xor(s, d);
  if (lane == 0) red[4 + w] = s;
  if (tid < 208) sSc[tid] = p;
  __syncthreads();
  float denom = red[4] + red[5] + red[6] + red[7] + 1e-30f;

  // pooled: re-gather h (L2-warm) weighted by attn; u32 loads, 2 rows per wave-pass
  {
    int hp = lane >> 5, hl = lane & 31;
    float a0 = 0.f, a1 = 0.f;
    for (int i = 0; i < 25; ++i) {
      int l = w * 50 + hp * 25 + i;
      unsigned hv = *(const unsigned*)(hist_b + (size_t)ids[l] * 64 + 2 * hl);
      float pw = sSc[l];
      a0 += pw * bf2f((unsigned short)(hv & 0xffff));
      a1 += pw * bf2f((unsigned short)(hv >> 16));
    }
    pbuf[(w * 2 + hp) * 64 + 2 * hl]     = a0;
    pbuf[(w * 2 + hp) * 64 + 2 * hl + 1] = a1;
  }
  __syncthreads();
  if (tid < 64) {
    float tot = 0.f;
#pragma unroll
    for (int c = 0; c < 8; ++c) tot += pbuf[c * 64 + tid];
    shared_p[(size_t)b * 256 + 180 + tid] = f2bf(tot / denom);
  }
}

// ---------------- k3b: experts (64-row tile x one expert per block) ----------------
__launch_bounds__(256, 2)
__global__ void k3b_experts(const unsigned short* __restrict__ shared_p,
                            const unsigned short* __restrict__ eW1t, const unsigned short* __restrict__ eW2t,
                            const float* __restrict__ eb1, const float* __restrict__ eb2,
                            unsigned short* __restrict__ eo_ws) {
  __shared__ unsigned short sX[64 * 256];   // X tile then reused as H1 tile (swizzled)
  __shared__ unsigned short sW[256 * 64];   // weight K-chunk, n-major (swizzled)
  int tid = threadIdx.x, w = tid >> 6, lane = tid & 63;
  int e = blockIdx.x & 7;
  int b0 = (blockIdx.x >> 3) * 64;
  int lr = lane & 15, g = lane >> 4;

  for (int j = tid; j < 2048; j += 256) {
    int r = j >> 5, ke = (j & 31) * 8;
    uint4 v = *(const uint4*)(shared_p + (size_t)(b0 + r) * 256 + ke);
    *(uint4*)(sX + r * 256 + SWZ(r, ke)) = v;
  }
  f32x4 acc[16];
#pragma unroll
  for (int i = 0; i < 16; ++i) acc[i] = (f32x4){0.f, 0.f, 0.f, 0.f};
  const unsigned short* w1 = eW1t + (size_t)e * 256 * 256;
  for (int c = 0; c < 4; ++c) {
    __syncthreads();
    for (int j = tid; j < 2048; j += 256) {
      int n = j >> 3, ke = (j & 7) * 8;
      uint4 v = *(const uint4*)(w1 + n * 256 + c * 64 + ke);
      *(uint4*)(sW + n * 64 + SWZ(n, ke)) = v;
    }
    __syncthreads();
    int m = w * 16 + lr;
#pragma unroll
    for (int kk = 0; kk < 2; ++kk) {
      int kabs = c * 64 + kk * 32 + g * 8;
      bfrag a = *(const bfrag*)(sX + m * 256 + SWZ(m, kabs));
      int kloc = kk * 32 + g * 8;
#pragma unroll
      for (int nt = 0; nt < 16; ++nt) {
        int n = nt * 16 + lr;
        bfrag bb = *(const bfrag*)(sW + n * 64 + SWZ(n, kloc));
        acc[nt] = __builtin_amdgcn_mfma_f32_16x16x32_bf16(a, bb, acc[nt], 0, 0, 0);
      }
    }
  }
  __syncthreads();
  // h1 = relu(acc + eb1) -> reuse sX
#pragma unroll
  for (int nt = 0; nt < 16; ++nt) {
    int n = nt * 16 + lr;
    float bb = eb1[e * 256 + n];
#pragma unroll
    for (int r = 0; r < 4; ++r) {
      float vv = fmaxf(acc[nt][r] + bb, 0.f);
      int mm = w * 16 + g * 4 + r;
      sX[mm * 256 + SWZ(mm, n)] = f2bf(vv);
    }
  }
  f32x4 acc2[8];
#pragma unroll
  for (int i = 0; i < 8; ++i) acc2[i] = (f32x4){0.f, 0.f, 0.f, 0.f};
  const unsigned short* w2 = eW2t + (size_t)e * 128 * 256;
  for (int c = 0; c < 4; ++c) {
    __syncthreads();
    for (int j = tid; j < 1024; j += 256) {
      int n = j >> 3, ke = (j & 7) * 8;
      uint4 v = *(const uint4*)(w2 + n * 256 + c * 64 + ke);
      *(uint4*)(sW + n * 64 + SWZ(n, ke)) = v;
    }
    __syncthreads();
    int m = w * 16 + lr;
#pragma unroll
    for (int kk = 0; kk < 2; ++kk) {
      int kabs = c * 64 + kk * 32 + g * 8;
      bfrag a = *(const bfrag*)(sX + m * 256 + SWZ(m, kabs));
      int kloc = kk * 32 + g * 8;
#pragma unroll
      for (int nt = 0; nt < 8; ++nt) {
        int n = nt * 16 + lr;
        bfrag bb = *(const bfrag*)(sW + n * 64 + SWZ(n, kloc));
        acc2[nt] = __builtin_amdgcn_mfma_f32_16x16x32_bf16(a, bb, acc2[nt], 0, 0, 0);
      }
    }
  }
#pragma unroll
  for (int nt = 0; nt < 8; ++nt) {
    int n = nt * 16 + lr;
    float bb = eb2[e * 128 + n];
#pragma unroll
    for (int r = 0; r < 4; ++r) {
      float vv = fmaxf(acc2[nt][r] + bb, 0.f);
      int mm = w * 16 + g * 4 + r;
      eo_ws[((size_t)(b0 + mm) * 8 + e) * 128 + n] = f2bf(vv);
    }
  }
}

// ---------------- k4: gates + mixture + towers + sigmoid ----------------
__launch_bounds__(256, 1)
__global__ void k4_tail(const unsigned short* __restrict__ shared_p, const unsigned short* __restrict__ eo_ws,
                        const float* __restrict__ gW, const float* __restrict__ gb,
                        const float* __restrict__ tW1, const float* __restrict__ tb1,
                        const float* __restrict__ tW2, const float* __restrict__ tb2,
                        const float* __restrict__ tW3, const float* __restrict__ tb3,
                        float* __restrict__ out) {
  __shared__ float gWt[2 * 8 * 256];     // [t][e][c] (c padded to 256)
  __shared__ float sT1[2 * 128 * 64];
  __shared__ float sT2[2 * 64 * 32];
  __shared__ float sT3[64], sB1[128], sB2[64], sB3[2], sGb[16];
  __shared__ float tiBuf[4][2][128];
  __shared__ float x1Buf[4][2][64];
  int tid = threadIdx.x, w = tid >> 6, lane = tid & 63;
  for (int i = tid; i < 2 * 8 * 256; i += 256) {
    int t = i >> 11, e = (i >> 8) & 7, c = i & 255;
    gWt[i] = (c < 244) ? gW[(t * 244 + c) * 8 + e] : 0.f;
  }
  for (int i = tid; i < 2 * 128 * 64; i += 256) sT1[i] = tW1[i];
  for (int i = tid; i < 2 * 64 * 32; i += 256) sT2[i] = tW2[i];
  if (tid < 64) sT3[tid] = tW3[tid];
  if (tid < 128) sB1[tid] = tb1[tid];
  if (tid < 64) sB2[tid] = tb2[tid];
  if (tid < 2) sB3[tid] = tb3[tid];
  if (tid < 16) sGb[tid] = gb[tid];
  __syncthreads();
  int b0 = blockIdx.x * 8;
  for (int it = 0; it < 2; ++it) {
    int b = b0 + it * 4 + w;
    const unsigned short* srow = shared_p + (size_t)b * 256;
    float s0 = bf2f(srow[lane]), s1 = bf2f(srow[64 + lane]);
    float s2 = bf2f(srow[128 + lane]), s3 = bf2f(srow[192 + lane]);
    float part[16];
#pragma unroll
    for (int te = 0; te < 16; ++te) {
      const float* gr = gWt + te * 256;
      part[te] = s0 * gr[lane] + s1 * gr[64 + lane] + s2 * gr[128 + lane] + s3 * gr[192 + lane];
    }
#pragma unroll
    for (int d = 1; d < 64; d <<= 1)
#pragma unroll
      for (int te = 0; te < 16; ++te) part[te] += __shfl_xor(part[te], d);
    float gate[16];
#pragma unroll
    for (int t = 0; t < 2; ++t) {
      float mxv = -3e38f;
#pragma unroll
      for (int e = 0; e < 8; ++e) mxv = fmaxf(mxv, part[t * 8 + e] + sGb[t * 8 + e]);
      float sum = 0.f;
#pragma unroll
      for (int e = 0; e < 8; ++e) {
        float pe = expf(part[t * 8 + e] + sGb[t * 8 + e] - mxv);
        gate[t * 8 + e] = pe; sum += pe;
      }
      float inv = 1.f / sum;
#pragma unroll
      for (int e = 0; e < 8; ++e) gate[t * 8 + e] *= inv;
    }
    float ti0a = 0.f, ti0b = 0.f, ti1a = 0.f, ti1b = 0.f;
    const unsigned short* eor = eo_ws + (size_t)b * 1024;
#pragma unroll
    for (int e = 0; e < 8; ++e) {
      float ea = bf2f(eor[e * 128 + lane]);
      float eb = bf2f(eor[e * 128 + 64 + lane]);
      ti0a += gate[e] * ea;     ti0b += gate[e] * eb;
      ti1a += gate[8 + e] * ea; ti1b += gate[8 + e] * eb;
    }
    tiBuf[w][0][lane] = ti0a; tiBuf[w][0][64 + lane] = ti0b;
    tiBuf[w][1][lane] = ti1a; tiBuf[w][1][64 + lane] = ti1b;
    __syncthreads();
#pragma unroll
    for (int t = 0; t < 2; ++t) {
      float x = sB1[t * 64 + lane];
      const float* wt = sT1 + t * 8192;
      const float* tb = tiBuf[w][t];
#pragma unroll 4
      for (int k = 0; k < 128; ++k) x += tb[k] * wt[k * 64 + lane];
      x1Buf[w][t][lane] = fmaxf(x, 0.f);
    }
    __syncthreads();
    {
      int t = lane >> 5, j2 = lane & 31;
      float x = sB2[t * 32 + j2];
      const float* wt = sT2 + t * 2048;
      const float* xb = x1Buf[w][t];
#pragma unroll 4
      for (int k = 0; k < 64; ++k) x += xb[k] * wt[k * 32 + j2];
      x = fmaxf(x, 0.f);
      float pr = x * sT3[t * 32 + j2];
#pragma unroll
      for (int d = 1; d < 32; d <<= 1) pr += __shfl_xor(pr, d);
      if (j2 == 0) {
        float logit = pr + sB3[t];
        out[(size_t)t * 16384 + b] = 1.f / (1.f + expf(-logit));
      }
    }
    __syncthreads();
  }
}

// ---------------- launcher ----------------
extern "C" void kernel_launch(void* const* d_in, const int* in_sizes, int n_in,
                              void* d_out, int out_size, void* d_ws, size_t ws_size,
                              hipStream_t stream) {
  const int*   user_id    = (const int*)  d_in[0];
  const int*   item_id    = (const int*)  d_in[1];
  const int*   item_cat   = (const int*)  d_in[2];
  const int*   item_dur   = (const int*)  d_in[3];
  const float* user_dense = (const float*)d_in[4];
  const float* item_dense = (const float*)d_in[5];
  const int*   hist_seq   = (const int*)  d_in[6];
  const float* user_E     = (const float*)d_in[7];
  const float* item_E     = (const float*)d_in[8];
  const float* cat_E      = (const float*)d_in[9];
  const float* dur_E      = (const float*)d_in[10];
  const float* hist_E     = (const float*)d_in[11];
  const float* Wproj      = (const float*)d_in[12];
  const float* aW1        = (const float*)d_in[13];
  const float* ab1        = (const float*)d_in[14];
  const float* aW2        = (const float*)d_in[15];
  const float* ab2        = (const float*)d_in[16];
  const float* aW3        = (const float*)d_in[17];
  // d_in[18] = ab3: cancels in softmax, unused
  const float* eW1        = (const float*)d_in[19];
  const float* eb1        = (const float*)d_in[20];
  const float* eW2        = (const float*)d_in[21];
  const float* eb2        = (const float*)d_in[22];
  const float* gW         = (const float*)d_in[23];
  const float* gb         = (const float*)d_in[24];
  const float* tW1        = (const float*)d_in[25];
  const float* tb1        = (const float*)d_in[26];
  const float* tW2        = (const float*)d_in[27];
  const float* tb2        = (const float*)d_in[28];
  const float* tW3        = (const float*)d_in[29];
  const float* tb3        = (const float*)d_in[30];
  float* out = (float*)d_out;
  char* ws = (char*)d_ws;

  unsigned short* attnBt  = (unsigned short*)(ws + WS_ATTNB);
  unsigned short* aW2t    = (unsigned short*)(ws + WS_AW2T);
  float*          A13     = (float*)         (ws + WS_A13);
  unsigned short* eW1t    = (unsigned short*)(ws + WS_EW1T);
  unsigned short* eW2t    = (unsigned short*)(ws + WS_EW2T);
  unsigned short* hist_b  = (unsigned short*)(ws + WS_HISTB);
  unsigned short* tgt     = (unsigned short*)(ws + WS_TGT);
  float*          tA      = (float*)         (ws + WS_TA);
  unsigned short* shared_p= (unsigned short*)(ws + WS_SHP);
  unsigned short* eo_ws   = (unsigned short*)(ws + WS_EO);

  k0_prep<<<2048, 256, 0, stream>>>(aW1, aW2, eW1, eW2, hist_E,
                                    attnBt, aW2t, A13, eW1t, eW2t, hist_b);
  k1_tgt<<<1024, 256, 0, stream>>>(item_id, item_E, Wproj, A13, ab1, tgt, tA);
  k3a_assemble<<<4096, 256, 0, stream>>>(user_id, item_id, item_cat, item_dur,
                                         user_dense, item_dense, user_E, item_E,
                                         cat_E, dur_E, shared_p);
  k2_attn<<<16384, 256, 0, stream>>>(hist_seq, hist_b, tgt, tA, attnBt, aW2t,
                                     ab2, aW3, shared_p);
  k3b_experts<<<2048, 256, 0, stream>>>(shared_p, eW1t, eW2t, eb1, eb2, eo_ws);
  k4_tail<<<2048, 256, 0, stream>>>(shared_p, eo_ws, gW, gb, tW1, tb1, tW2, tb2,
                                    tW3, tb3, out);
}

// Round 4
// 260.006 us; speedup vs baseline: 6.6649x; 1.5398x over previous
//
#include <hip/hip_runtime.h>
#include <cstdint>
#include <cmath>

// MMoE forward, MI355X. B=16384 L=200 SD=64 CONCAT=244 NE=8 EH=256 EO=128 NT=2.
// R2: k2 occupancy rebuild. R3: per-batch M-fold in k2. R4: k4 rewritten as MFMA
// tail (gates/tower1/tower2 via MFMA, weights bf16 from k0, no bulk LDS preload).

typedef __attribute__((ext_vector_type(8))) short bfrag;   // 8 x bf16 (A/B frag)
typedef __attribute__((ext_vector_type(4))) float f32x4;   // C/D frag

__device__ __forceinline__ unsigned short f2bf(float f) {
  union { float f; unsigned u; } v; v.f = f;
  unsigned r = v.u + 0x7FFFu + ((v.u >> 16) & 1u);
  return (unsigned short)(r >> 16);
}
__device__ __forceinline__ float bf2f(unsigned short b) {
  union { unsigned u; float f; } v; v.u = ((unsigned)b) << 16;
  return v.f;
}

#define SWZ(row, col) ((col) ^ (((row) & 7) << 3))   // element-unit XOR swizzle (16B chunks)

// ---------------- workspace layout (bytes) ----------------
static constexpr size_t WS_ATTNB = 0;                       // bf16 [64][128]  (n-major: [n][k])
static constexpr size_t WS_AW2T  = WS_ATTNB + 16384;        // bf16 [16][64]
static constexpr size_t WS_A13   = WS_AW2T + 2048;          // f32  [64][64]   ([k][n])
static constexpr size_t WS_EW1T  = WS_A13 + 16384;          // bf16 [8][256][256] ([e][n][k], k>=244 zero)
static constexpr size_t WS_EW2T  = WS_EW1T + 1048576;       // bf16 [8][128][256] ([e][n][k])
static constexpr size_t WS_HISTB = WS_EW2T + 524288;        // bf16 [100001][64]
static constexpr size_t WS_TGT   = WS_HISTB + 12800256;     // bf16 [B][64]
static constexpr size_t WS_TA    = WS_TGT + 2097152;        // f32  [B][64]
static constexpr size_t WS_SHP   = WS_TA + 4194304;         // bf16 [B][256] (padded shared)
static constexpr size_t WS_EO    = WS_SHP + 8388608;        // bf16 [B][8][128]
static constexpr size_t WS_GWB   = WS_EO + 33554432;        // bf16 [16][256]    (gate W, n-major, k pad 256)
static constexpr size_t WS_TW1B  = WS_GWB + 8192;           // bf16 [2][64][128] (tower1 W, n-major)
static constexpr size_t WS_TW2B  = WS_TW1B + 32768;         // bf16 [2][32][64]  (tower2 W, n-major)
// total = WS_TW2B + 8192 = 62,691,328 bytes of d_ws

// ---------------- k0: fold/transpose/bf16-cast weights + hist table ----------------
__launch_bounds__(256)
__global__ void k0_prep(const float* __restrict__ aW1, const float* __restrict__ aW2,
                        const float* __restrict__ eW1, const float* __restrict__ eW2,
                        const float* __restrict__ hist_E,
                        const float* __restrict__ gW, const float* __restrict__ tW1,
                        const float* __restrict__ tW2,
                        unsigned short* __restrict__ attnBt, unsigned short* __restrict__ aW2t,
                        float* __restrict__ A13,
                        unsigned short* __restrict__ eW1t, unsigned short* __restrict__ eW2t,
                        unsigned short* __restrict__ hist_b,
                        unsigned short* __restrict__ gWb, unsigned short* __restrict__ tW1b,
                        unsigned short* __restrict__ tW2b) {
  int tid = blockIdx.x * blockDim.x + threadIdx.x;
  int nth = gridDim.x * blockDim.x;
  // attnBt[n][k]: k<64 -> A2-A3 (h part), k>=64 -> A4 (t*h part)
  for (int i = tid; i < 64 * 128; i += nth) {
    int n = i >> 7, k = i & 127;
    float v = (k < 64) ? (aW1[(64 + k) * 64 + n] - aW1[(128 + k) * 64 + n])
                       : aW1[(128 + k) * 64 + n];
    attnBt[i] = f2bf(v);
  }
  // A13[k][n] = A1 + A3 (f32, for exact tA)
  for (int i = tid; i < 64 * 64; i += nth) {
    int k = i >> 6, n = i & 63;
    A13[i] = aW1[k * 64 + n] + aW1[(128 + k) * 64 + n];
  }
  // aW2t[n][k]
  for (int i = tid; i < 16 * 64; i += nth) {
    int n = i >> 6, k = i & 63;
    aW2t[i] = f2bf(aW2[k * 16 + n]);
  }
  // eW1t[e][n][k] (k<244 valid else 0)
  for (int i = tid; i < 8 * 256 * 256; i += nth) {
    int e = i >> 16, n = (i >> 8) & 255, k = i & 255;
    eW1t[i] = (k < 244) ? f2bf(eW1[(e * 244 + k) * 256 + n]) : (unsigned short)0;
  }
  // eW2t[e][n][k]
  for (int i = tid; i < 8 * 128 * 256; i += nth) {
    int e = i >> 15, n = (i >> 8) & 127, k = i & 255;
    eW2t[i] = f2bf(eW2[(e * 256 + k) * 128 + n]);
  }
  // gWb[n=t*8+e][k] (k pad 256)
  for (int i = tid; i < 16 * 256; i += nth) {
    int n = i >> 8, k = i & 255, t = n >> 3, e = n & 7;
    gWb[i] = (k < 244) ? f2bf(gW[(t * 244 + k) * 8 + e]) : (unsigned short)0;
  }
  // tW1b[t][n][k]
  for (int i = tid; i < 2 * 64 * 128; i += nth) {
    int t = i >> 13, n = (i >> 7) & 63, k = i & 127;
    tW1b[i] = f2bf(tW1[(t * 128 + k) * 64 + n]);
  }
  // tW2b[t][n][k]
  for (int i = tid; i < 2 * 32 * 64; i += nth) {
    int t = i >> 11, n = (i >> 6) & 31, k = i & 63;
    tW2b[i] = f2bf(tW2[(t * 64 + k) * 32 + n]);
  }
  // bf16 hist table (halves gather traffic in k2)
  for (int i = tid; i < 100001 * 64; i += nth) hist_b[i] = f2bf(hist_E[i]);
}

// ---------------- k1: t = i_emb @ Wproj ; tA = t @ (A1+A3) + ab1 ----------------
__launch_bounds__(256)
__global__ void k1_tgt(const int* __restrict__ item_id, const float* __restrict__ item_E,
                       const float* __restrict__ Wproj, const float* __restrict__ A13,
                       const float* __restrict__ ab1,
                       unsigned short* __restrict__ tgt, float* __restrict__ tA) {
  __shared__ float Wp[64 * 64], A13s[64 * 64], ab1s[64];
  __shared__ float ivb[4][64], tbuf[4][64];
  int tid = threadIdx.x, w = tid >> 6, lane = tid & 63;
  for (int i = tid; i < 4096; i += 256) { Wp[i] = Wproj[i]; A13s[i] = A13[i]; }
  if (tid < 64) ab1s[tid] = ab1[tid];
  __syncthreads();
  int b0 = blockIdx.x * 16;
  for (int it = 0; it < 4; ++it) {
    int b = b0 + w * 4 + it;
    int iid = item_id[b];
    ivb[w][lane] = item_E[(size_t)iid * 64 + lane];
    __syncthreads();
    float t = 0.f;
#pragma unroll 8
    for (int k = 0; k < 64; ++k) t += ivb[w][k] * Wp[k * 64 + lane];
    tbuf[w][lane] = t;
    __syncthreads();
    float ta = ab1s[lane];
#pragma unroll 8
    for (int k = 0; k < 64; ++k) ta += tbuf[w][k] * A13s[k * 64 + lane];
    tgt[(size_t)b * 64 + lane] = f2bf(t);
    tA[(size_t)b * 64 + lane] = ta;
  }
}

// ---------------- k3a: assemble shared (cols 0..179, pad 244..255) ----------------
__launch_bounds__(256)
__global__ void k3a_assemble(const int* __restrict__ user_id, const int* __restrict__ item_id,
                             const int* __restrict__ item_cat, const int* __restrict__ item_dur,
                             const float* __restrict__ user_dense, const float* __restrict__ item_dense,
                             const float* __restrict__ user_E, const float* __restrict__ item_E,
                             const float* __restrict__ cat_E, const float* __restrict__ dur_E,
                             unsigned short* __restrict__ shared_p) {
  int tid = threadIdx.x, w = tid >> 6, lane = tid & 63;
  int b = blockIdx.x * 4 + w;
  unsigned short* row = shared_p + (size_t)b * 256;
  row[lane]      = f2bf(user_E[(size_t)user_id[b] * 64 + lane]);
  row[64 + lane] = f2bf(item_E[(size_t)item_id[b] * 64 + lane]);
  if (lane < 16) row[128 + lane] = f2bf(cat_E[item_cat[b] * 16 + lane]);
  if (lane < 8)  row[144 + lane] = f2bf(dur_E[item_dur[b] * 8 + lane]);
  if (lane < 25) row[152 + lane] = f2bf(user_dense[b * 25 + lane]);
  if (lane < 3)  row[177 + lane] = f2bf(item_dense[b * 3 + lane]);
  if (lane < 12) row[244 + lane] = 0;
}

// ---------------- k2: fused DIN attention per batch element (M-fold, high occupancy) ----------------
__launch_bounds__(256, 5)
__global__ void k2_attn(const int* __restrict__ hist_seq, const unsigned short* __restrict__ hist_b,
                        const unsigned short* __restrict__ tgt, const float* __restrict__ tA,
                        const unsigned short* __restrict__ attnBt_g, const unsigned short* __restrict__ aW2t_g,
                        const float* __restrict__ ab2, const float* __restrict__ aW3,
                        unsigned short* __restrict__ shared_p) {
  __shared__ unsigned short sH1[208 * 64];   // layer1 output bf16 (swizzled); first 4096 transiently hold M
  __shared__ int   ids[208];
  __shared__ float tv[64], tAv[64];
  __shared__ float sSc[208];
  __shared__ float red[8];
  __shared__ float pbuf[512];
  int b = blockIdx.x;
  int tid = threadIdx.x, w = tid >> 6, lane = tid & 63;
  int lr = lane & 15, g = lane >> 4;

  if (tid < 208) ids[tid] = (tid < 200) ? hist_seq[(size_t)b * 200 + tid] : 0;
  if (tid < 64) tv[tid] = bf2f(tgt[(size_t)b * 64 + tid]);
  else if (tid < 128) tAv[tid - 64] = tA[(size_t)b * 64 + (tid - 64)];

  // layer-2 B fragments straight from global (L2-resident)
  bfrag b2fr[2];
#pragma unroll
  for (int kk = 0; kk < 2; ++kk)
    b2fr[kk] = *(const bfrag*)(aW2t_g + lr * 64 + kk * 32 + g * 8);
  float ab2v = ab2[lr];
  float aW3v = aW3[lr];
  __syncthreads();   // tv ready

  // cooperative M[n][k] = A23[n][k] + t[k]*A4[n][k]  into sH1[0:4096] (row stride 64, swizzled)
  {
    int n = tid >> 2, k0 = (tid & 3) * 16;
    const unsigned short* rowp = attnBt_g + n * 128;
    unsigned short a23[16], a4[16], mo[16];
    *(uint4*)(a23)     = *(const uint4*)(rowp + k0);
    *(uint4*)(a23 + 8) = *(const uint4*)(rowp + k0 + 8);
    *(uint4*)(a4)      = *(const uint4*)(rowp + 64 + k0);
    *(uint4*)(a4 + 8)  = *(const uint4*)(rowp + 64 + k0 + 8);
#pragma unroll
    for (int i = 0; i < 16; ++i)
      mo[i] = f2bf(bf2f(a23[i]) + tv[k0 + i] * bf2f(a4[i]));
    *(uint4*)(sH1 + n * 64 + SWZ(n, k0))     = *(uint4*)(mo);
    *(uint4*)(sH1 + n * 64 + SWZ(n, k0 + 8)) = *(uint4*)(mo + 8);
  }
  __syncthreads();   // M ready
  bfrag bfr[4][2];
#pragma unroll
  for (int nt = 0; nt < 4; ++nt)
#pragma unroll
    for (int kk = 0; kk < 2; ++kk) {
      int n = nt * 16 + lr;
      bfr[nt][kk] = *(const bfrag*)(sH1 + n * 64 + SWZ(n, kk * 32 + g * 8));
    }
  __syncthreads();   // all waves have M in regs; sH1 free for layer-1 output

  // layer 1: (208x64) @ (64x64) with per-batch folded M
  for (int mt = w; mt < 13; mt += 4) {
    int m = mt * 16 + lr;
    const unsigned short* hrow = hist_b + (size_t)ids[m] * 64;
    bfrag h0 = *(const bfrag*)(hrow + g * 8);          // k in [0,32)
    bfrag h1 = *(const bfrag*)(hrow + 32 + g * 8);     // k in [32,64)
    f32x4 acc[4] = {{0.f,0.f,0.f,0.f},{0.f,0.f,0.f,0.f},{0.f,0.f,0.f,0.f},{0.f,0.f,0.f,0.f}};
#pragma unroll
    for (int nt = 0; nt < 4; ++nt) {
      acc[nt] = __builtin_amdgcn_mfma_f32_16x16x32_bf16(h0, bfr[nt][0], acc[nt], 0, 0, 0);
      acc[nt] = __builtin_amdgcn_mfma_f32_16x16x32_bf16(h1, bfr[nt][1], acc[nt], 0, 0, 0);
    }
#pragma unroll
    for (int nt = 0; nt < 4; ++nt) {
      int n = nt * 16 + lr;
      float ta = tAv[n];
#pragma unroll
      for (int r = 0; r < 4; ++r) {
        float v = fmaxf(acc[nt][r] + ta, 0.f);
        int mm = mt * 16 + g * 4 + r;
        sH1[mm * 64 + SWZ(mm, n)] = f2bf(v);
      }
    }
  }
  __syncthreads();

  // layer 2: (208x64)@(64x16), + layer 3 dot via shuffle
  for (int mt = w; mt < 13; mt += 4) {
    f32x4 acc = {0.f, 0.f, 0.f, 0.f};
    int m = mt * 16 + lr;
#pragma unroll
    for (int kk = 0; kk < 2; ++kk) {
      int k0 = kk * 32 + g * 8;
      bfrag a = *(const bfrag*)(sH1 + m * 64 + SWZ(m, k0));
      acc = __builtin_amdgcn_mfma_f32_16x16x32_bf16(a, b2fr[kk], acc, 0, 0, 0);
    }
    float sc[4];
#pragma unroll
    for (int r = 0; r < 4; ++r) sc[r] = fmaxf(acc[r] + ab2v, 0.f) * aW3v;
#pragma unroll
    for (int d = 1; d < 16; d <<= 1)
#pragma unroll
      for (int r = 0; r < 4; ++r) sc[r] += __shfl_xor(sc[r], d);
    if (lr == 0) {
      int mr = mt * 16 + g * 4;
      sSc[mr] = sc[0]; sSc[mr + 1] = sc[1]; sSc[mr + 2] = sc[2]; sSc[mr + 3] = sc[3];
    }
  }
  __syncthreads();

  // masked softmax
  bool valid = false; float sc0 = 0.f;
  if (tid < 200 && ids[tid] != 0) { valid = true; sc0 = sSc[tid]; }
  float v = valid ? sc0 : -3.0e38f;
#pragma unroll
  for (int d = 1; d < 64; d <<= 1) v = fmaxf(v, __shfl_xor(v, d));
  if (lane == 0) red[w] = v;
  __syncthreads();
  float mx = fmaxf(fmaxf(red[0], red[1]), fmaxf(red[2], red[3]));
  float p = valid ? expf(sc0 - mx) : 0.f;
  float s = p;
#pragma unroll
  for (int d = 1; d < 64; d <<= 1) s += __shfl_xor(s, d);
  if (lane == 0) red[4 + w] = s;
  if (tid < 208) sSc[tid] = p;
  __syncthreads();
  float denom = red[4] + red[5] + red[6] + red[7] + 1e-30f;

  // pooled: re-gather h (L2-warm) weighted by attn; u32 loads, 2 rows per wave-pass
  {
    int hp = lane >> 5, hl = lane & 31;
    float a0 = 0.f, a1 = 0.f;
    for (int i = 0; i < 25; ++i) {
      int l = w * 50 + hp * 25 + i;
      unsigned hv = *(const unsigned*)(hist_b + (size_t)ids[l] * 64 + 2 * hl);
      float pw = sSc[l];
      a0 += pw * bf2f((unsigned short)(hv & 0xffff));
      a1 += pw * bf2f((unsigned short)(hv >> 16));
    }
    pbuf[(w * 2 + hp) * 64 + 2 * hl]     = a0;
    pbuf[(w * 2 + hp) * 64 + 2 * hl + 1] = a1;
  }
  __syncthreads();
  if (tid < 64) {
    float tot = 0.f;
#pragma unroll
    for (int c = 0; c < 8; ++c) tot += pbuf[c * 64 + tid];
    shared_p[(size_t)b * 256 + 180 + tid] = f2bf(tot / denom);
  }
}

// ---------------- k3b: experts (64-row tile x one expert per block) ----------------
__launch_bounds__(256, 2)
__global__ void k3b_experts(const unsigned short* __restrict__ shared_p,
                            const unsigned short* __restrict__ eW1t, const unsigned short* __restrict__ eW2t,
                            const float* __restrict__ eb1, const float* __restrict__ eb2,
                            unsigned short* __restrict__ eo_ws) {
  __shared__ unsigned short sX[64 * 256];   // X tile then reused as H1 tile (swizzled)
  __shared__ unsigned short sW[256 * 64];   // weight K-chunk, n-major (swizzled)
  int tid = threadIdx.x, w = tid >> 6, lane = tid & 63;
  int e = blockIdx.x & 7;
  int b0 = (blockIdx.x >> 3) * 64;
  int lr = lane & 15, g = lane >> 4;

  for (int j = tid; j < 2048; j += 256) {
    int r = j >> 5, ke = (j & 31) * 8;
    uint4 v = *(const uint4*)(shared_p + (size_t)(b0 + r) * 256 + ke);
    *(uint4*)(sX + r * 256 + SWZ(r, ke)) = v;
  }
  f32x4 acc[16];
#pragma unroll
  for (int i = 0; i < 16; ++i) acc[i] = (f32x4){0.f, 0.f, 0.f, 0.f};
  const unsigned short* w1 = eW1t + (size_t)e * 256 * 256;
  for (int c = 0; c < 4; ++c) {
    __syncthreads();
    for (int j = tid; j < 2048; j += 256) {
      int n = j >> 3, ke = (j & 7) * 8;
      uint4 v = *(const uint4*)(w1 + n * 256 + c * 64 + ke);
      *(uint4*)(sW + n * 64 + SWZ(n, ke)) = v;
    }
    __syncthreads();
    int m = w * 16 + lr;
#pragma unroll
    for (int kk = 0; kk < 2; ++kk) {
      int kabs = c * 64 + kk * 32 + g * 8;
      bfrag a = *(const bfrag*)(sX + m * 256 + SWZ(m, kabs));
      int kloc = kk * 32 + g * 8;
#pragma unroll
      for (int nt = 0; nt < 16; ++nt) {
        int n = nt * 16 + lr;
        bfrag bb = *(const bfrag*)(sW + n * 64 + SWZ(n, kloc));
        acc[nt] = __builtin_amdgcn_mfma_f32_16x16x32_bf16(a, bb, acc[nt], 0, 0, 0);
      }
    }
  }
  __syncthreads();
  // h1 = relu(acc + eb1) -> reuse sX
#pragma unroll
  for (int nt = 0; nt < 16; ++nt) {
    int n = nt * 16 + lr;
    float bb = eb1[e * 256 + n];
#pragma unroll
    for (int r = 0; r < 4; ++r) {
      float vv = fmaxf(acc[nt][r] + bb, 0.f);
      int mm = w * 16 + g * 4 + r;
      sX[mm * 256 + SWZ(mm, n)] = f2bf(vv);
    }
  }
  f32x4 acc2[8];
#pragma unroll
  for (int i = 0; i < 8; ++i) acc2[i] = (f32x4){0.f, 0.f, 0.f, 0.f};
  const unsigned short* w2 = eW2t + (size_t)e * 128 * 256;
  for (int c = 0; c < 4; ++c) {
    __syncthreads();
    for (int j = tid; j < 1024; j += 256) {
      int n = j >> 3, ke = (j & 7) * 8;
      uint4 v = *(const uint4*)(w2 + n * 256 + c * 64 + ke);
      *(uint4*)(sW + n * 64 + SWZ(n, ke)) = v;
    }
    __syncthreads();
    int m = w * 16 + lr;
#pragma unroll
    for (int kk = 0; kk < 2; ++kk) {
      int kabs = c * 64 + kk * 32 + g * 8;
      bfrag a = *(const bfrag*)(sX + m * 256 + SWZ(m, kabs));
      int kloc = kk * 32 + g * 8;
#pragma unroll
      for (int nt = 0; nt < 8; ++nt) {
        int n = nt * 16 + lr;
        bfrag bb = *(const bfrag*)(sW + n * 64 + SWZ(n, kloc));
        acc2[nt] = __builtin_amdgcn_mfma_f32_16x16x32_bf16(a, bb, acc2[nt], 0, 0, 0);
      }
    }
  }
#pragma unroll
  for (int nt = 0; nt < 8; ++nt) {
    int n = nt * 16 + lr;
    float bb = eb2[e * 128 + n];
#pragma unroll
    for (int r = 0; r < 4; ++r) {
      float vv = fmaxf(acc2[nt][r] + bb, 0.f);
      int mm = w * 16 + g * 4 + r;
      eo_ws[((size_t)(b0 + mm) * 8 + e) * 128 + n] = f2bf(vv);
    }
  }
}

// ---------------- k4: gates + mixture + towers + sigmoid (MFMA tail) ----------------
// 512 blocks x 32 rows. LDS ~26.5KB. Weights read from L2 (bf16, n-major).
__launch_bounds__(256, 3)
__global__ void k4_tail(const unsigned short* __restrict__ shared_p, const unsigned short* __restrict__ eo_ws,
                        const unsigned short* __restrict__ gWb, const float* __restrict__ gb,
                        const unsigned short* __restrict__ tW1b, const float* __restrict__ tb1,
                        const unsigned short* __restrict__ tW2b, const float* __restrict__ tb2,
                        const float* __restrict__ tW3, const float* __restrict__ tb3,
                        float* __restrict__ out) {
  __shared__ float sGL[32 * 17];            // gate logits -> gates (padded)
  __shared__ unsigned short sTi[2 * 32 * 128]; // ti bf16 (swizzled) 16KB
  __shared__ unsigned short sX1[2 * 32 * 64];  // x1 bf16 (swizzled) 8KB
  int tid = threadIdx.x, w = tid >> 6, lane = tid & 63;
  int lr = lane & 15, g = lane >> 4;
  int b0 = blockIdx.x * 32;

  // ---- Phase A: gate logits via MFMA (32x16, K=256); waves 0,1 ----
  if (w < 2) {
    int m = b0 + w * 16 + lr;
    f32x4 acc = {0.f, 0.f, 0.f, 0.f};
#pragma unroll
    for (int kk = 0; kk < 8; ++kk) {
      bfrag a = *(const bfrag*)(shared_p + (size_t)m * 256 + kk * 32 + g * 8);
      bfrag bb = *(const bfrag*)(gWb + lr * 256 + kk * 32 + g * 8);
      acc = __builtin_amdgcn_mfma_f32_16x16x32_bf16(a, bb, acc, 0, 0, 0);
    }
    float gbv = gb[lr];
#pragma unroll
    for (int r = 0; r < 4; ++r)
      sGL[(w * 16 + g * 4 + r) * 17 + lr] = acc[r] + gbv;
  }
  __syncthreads();

  // ---- softmax over 8 experts per (row, task) ----
  if (tid < 64) {
    int row = tid >> 1, t = tid & 1;
    float* p = sGL + row * 17 + t * 8;
    float mx = -3e38f;
#pragma unroll
    for (int e = 0; e < 8; ++e) mx = fmaxf(mx, p[e]);
    float sum = 0.f; float pe[8];
#pragma unroll
    for (int e = 0; e < 8; ++e) { pe[e] = expf(p[e] - mx); sum += pe[e]; }
    float inv = 1.f / sum;
#pragma unroll
    for (int e = 0; e < 8; ++e) p[e] = pe[e] * inv;
  }
  __syncthreads();

  // ---- Phase B: mixture ti[t][row][o] = sum_e gate * eo ; 8 threads/row ----
  {
    int row = tid >> 3, q = tid & 7, t = q >> 2, o0 = (q & 3) * 32;
    const float* gp = sGL + row * 17 + t * 8;
    float acc[32];
#pragma unroll
    for (int j = 0; j < 32; ++j) acc[j] = 0.f;
    const unsigned short* base = eo_ws + ((size_t)(b0 + row) * 8) * 128 + o0;
#pragma unroll
    for (int e = 0; e < 8; ++e) {
      float ge = gp[e];
      const unsigned short* p = base + e * 128;
#pragma unroll
      for (int c = 0; c < 4; ++c) {
        uint4 v = *(const uint4*)(p + c * 8);
        const unsigned short* u = (const unsigned short*)&v;
#pragma unroll
        for (int j = 0; j < 8; ++j) acc[c * 8 + j] += ge * bf2f(u[j]);
      }
    }
    unsigned short ob[32];
#pragma unroll
    for (int j = 0; j < 32; ++j) ob[j] = f2bf(acc[j]);
#pragma unroll
    for (int c = 0; c < 4; ++c)
      *(uint4*)(sTi + t * 4096 + row * 128 + SWZ(row, o0 + c * 8)) = *(const uint4*)(ob + c * 8);
  }
  __syncthreads();

  // ---- Phase C: tower1 via MFMA; wave w -> (t = w>>1, mt = w&1); 32x64 K=128 ----
  int t = w >> 1, mt = w & 1;
  {
    f32x4 acc[4] = {{0.f,0.f,0.f,0.f},{0.f,0.f,0.f,0.f},{0.f,0.f,0.f,0.f},{0.f,0.f,0.f,0.f}};
    int ml = mt * 16 + lr;
#pragma unroll
    for (int kk = 0; kk < 4; ++kk) {
      bfrag a = *(const bfrag*)(sTi + t * 4096 + ml * 128 + SWZ(ml, kk * 32 + g * 8));
#pragma unroll
      for (int nt = 0; nt < 4; ++nt) {
        bfrag bb = *(const bfrag*)(tW1b + t * 8192 + (nt * 16 + lr) * 128 + kk * 32 + g * 8);
        acc[nt] = __builtin_amdgcn_mfma_f32_16x16x32_bf16(a, bb, acc[nt], 0, 0, 0);
      }
    }
#pragma unroll
    for (int nt = 0; nt < 4; ++nt) {
      int n = nt * 16 + lr;
      float bias = tb1[t * 64 + n];
#pragma unroll
      for (int r = 0; r < 4; ++r) {
        float x = fmaxf(acc[nt][r] + bias, 0.f);
        int row = mt * 16 + g * 4 + r;
        sX1[t * 2048 + row * 64 + SWZ(row, n)] = f2bf(x);
      }
    }
  }
  __syncthreads();

  // ---- Phase D: tower2 MFMA (32x32 K=64) + tower3 dot + sigmoid ----
  {
    f32x4 acc[2] = {{0.f,0.f,0.f,0.f},{0.f,0.f,0.f,0.f}};
    int ml = mt * 16 + lr;
#pragma unroll
    for (int kk = 0; kk < 2; ++kk) {
      bfrag a = *(const bfrag*)(sX1 + t * 2048 + ml * 64 + SWZ(ml, kk * 32 + g * 8));
#pragma unroll
      for (int nt = 0; nt < 2; ++nt) {
        bfrag bb = *(const bfrag*)(tW2b + t * 2048 + (nt * 16 + lr) * 64 + kk * 32 + g * 8);
        acc[nt] = __builtin_amdgcn_mfma_f32_16x16x32_bf16(a, bb, acc[nt], 0, 0, 0);
      }
    }
    float part[4] = {0.f, 0.f, 0.f, 0.f};
#pragma unroll
    for (int nt = 0; nt < 2; ++nt) {
      int n = nt * 16 + lr;
      float bias = tb2[t * 32 + n];
      float w3 = tW3[t * 32 + n];
#pragma unroll
      for (int r = 0; r < 4; ++r)
        part[r] += fmaxf(acc[nt][r] + bias, 0.f) * w3;
    }
#pragma unroll
    for (int d = 1; d < 16; d <<= 1)
#pragma unroll
      for (int r = 0; r < 4; ++r) part[r] += __shfl_xor(part[r], d);
    if (lr == 0) {
      float b3 = tb3[t];
#pragma unroll
      for (int r = 0; r < 4; ++r) {
        float logit = part[r] + b3;
        out[(size_t)t * 16384 + b0 + mt * 16 + g * 4 + r] = 1.f / (1.f + expf(-logit));
      }
    }
  }
}

// ---------------- launcher ----------------
extern "C" void kernel_launch(void* const* d_in, const int* in_sizes, int n_in,
                              void* d_out, int out_size, void* d_ws, size_t ws_size,
                              hipStream_t stream) {
  const int*   user_id    = (const int*)  d_in[0];
  const int*   item_id    = (const int*)  d_in[1];
  const int*   item_cat   = (const int*)  d_in[2];
  const int*   item_dur   = (const int*)  d_in[3];
  const float* user_dense = (const float*)d_in[4];
  const float* item_dense = (const float*)d_in[5];
  const int*   hist_seq   = (const int*)  d_in[6];
  const float* user_E     = (const float*)d_in[7];
  const float* item_E     = (const float*)d_in[8];
  const float* cat_E      = (const float*)d_in[9];
  const float* dur_E      = (const float*)d_in[10];
  const float* hist_E     = (const float*)d_in[11];
  const float* Wproj      = (const float*)d_in[12];
  const float* aW1        = (const float*)d_in[13];
  const float* ab1        = (const float*)d_in[14];
  const float* aW2        = (const float*)d_in[15];
  const float* ab2        = (const float*)d_in[16];
  const float* aW3        = (const float*)d_in[17];
  // d_in[18] = ab3: cancels in softmax, unused
  const float* eW1        = (const float*)d_in[19];
  const float* eb1        = (const float*)d_in[20];
  const float* eW2        = (const float*)d_in[21];
  const float* eb2        = (const float*)d_in[22];
  const float* gW         = (const float*)d_in[23];
  const float* gb         = (const float*)d_in[24];
  const float* tW1        = (const float*)d_in[25];
  const float* tb1        = (const float*)d_in[26];
  const float* tW2        = (const float*)d_in[27];
  const float* tb2        = (const float*)d_in[28];
  const float* tW3        = (const float*)d_in[29];
  const float* tb3        = (const float*)d_in[30];
  float* out = (float*)d_out;
  char* ws = (char*)d_ws;

  unsigned short* attnBt  = (unsigned short*)(ws + WS_ATTNB);
  unsigned short* aW2t    = (unsigned short*)(ws + WS_AW2T);
  float*          A13     = (float*)         (ws + WS_A13);
  unsigned short* eW1t    = (unsigned short*)(ws + WS_EW1T);
  unsigned short* eW2t    = (unsigned short*)(ws + WS_EW2T);
  unsigned short* hist_b  = (unsigned short*)(ws + WS_HISTB);
  unsigned short* tgt     = (unsigned short*)(ws + WS_TGT);
  float*          tA      = (float*)         (ws + WS_TA);
  unsigned short* shared_p= (unsigned short*)(ws + WS_SHP);
  unsigned short* eo_ws   = (unsigned short*)(ws + WS_EO);
  unsigned short* gWb     = (unsigned short*)(ws + WS_GWB);
  unsigned short* tW1b    = (unsigned short*)(ws + WS_TW1B);
  unsigned short* tW2b    = (unsigned short*)(ws + WS_TW2B);

  k0_prep<<<2048, 256, 0, stream>>>(aW1, aW2, eW1, eW2, hist_E, gW, tW1, tW2,
                                    attnBt, aW2t, A13, eW1t, eW2t, hist_b,
                                    gWb, tW1b, tW2b);
  k1_tgt<<<1024, 256, 0, stream>>>(item_id, item_E, Wproj, A13, ab1, tgt, tA);
  k3a_assemble<<<4096, 256, 0, stream>>>(user_id, item_id, item_cat, item_dur,
                                         user_dense, item_dense, user_E, item_E,
                                         cat_E, dur_E, shared_p);
  k2_attn<<<16384, 256, 0, stream>>>(hist_seq, hist_b, tgt, tA, attnBt, aW2t,
                                     ab2, aW3, shared_p);
  k3b_experts<<<2048, 256, 0, stream>>>(shared_p, eW1t, eW2t, eb1, eb2, eo_ws);
  k4_tail<<<512, 256, 0, stream>>>(shared_p, eo_ws, gWb, gb, tW1b, tb1, tW2b, tb2,
                                   tW3, tb3, out);
}

// Round 6
// 257.880 us; speedup vs baseline: 6.7199x; 1.0082x over previous
//
#include <hip/hip_runtime.h>
#include <hip/hip_bf16.h>
#include <cstdint>
#include <cmath>

// MMoE forward, MI355X. B=16384 L=200 SD=64 CONCAT=244 NE=8 EH=256 EO=128 NT=2.
// R2: k2 occupancy rebuild. R3: per-batch M-fold in k2. R4: MFMA k4 tail.
// R5: HW bf16 cvt, cheap unpack, __expf. R6: fix bfHi scaling bug (no 2^-16 —
// hv&0xffff0000 already IS the high bf16's float bits).

typedef __attribute__((ext_vector_type(8))) short bfrag;   // 8 x bf16 (A/B frag)
typedef __attribute__((ext_vector_type(4))) float f32x4;   // C/D frag

__device__ __forceinline__ unsigned short f2bf(float f) {
  __hip_bfloat16 h = __float2bfloat16(f);          // HW v_cvt on gfx950 (RNE)
  return __builtin_bit_cast(unsigned short, h);
}
__device__ __forceinline__ float bf2f(unsigned short b) {
  union { unsigned u; float f; } v; v.u = ((unsigned)b) << 16;
  return v.f;
}
__device__ __forceinline__ float bfLo(unsigned hv) {   // low bf16 of a packed pair
  union { unsigned u; float f; } v; v.u = hv << 16;
  return v.f;
}
__device__ __forceinline__ float bfHi(unsigned hv) {   // high bf16 of a packed pair (exact, no scale)
  union { unsigned u; float f; } v; v.u = hv & 0xffff0000u;
  return v.f;
}

#define SWZ(row, col) ((col) ^ (((row) & 7) << 3))   // element-unit XOR swizzle (16B chunks)

// ---------------- workspace layout (bytes) ----------------
static constexpr size_t WS_ATTNB = 0;                       // bf16 [64][128]  (n-major: [n][k])
static constexpr size_t WS_AW2T  = WS_ATTNB + 16384;        // bf16 [16][64]
static constexpr size_t WS_A13   = WS_AW2T + 2048;          // f32  [64][64]   ([k][n])
static constexpr size_t WS_EW1T  = WS_A13 + 16384;          // bf16 [8][256][256] ([e][n][k], k>=244 zero)
static constexpr size_t WS_EW2T  = WS_EW1T + 1048576;       // bf16 [8][128][256] ([e][n][k])
static constexpr size_t WS_HISTB = WS_EW2T + 524288;        // bf16 [100001][64]
static constexpr size_t WS_TGT   = WS_HISTB + 12800256;     // bf16 [B][64]
static constexpr size_t WS_TA    = WS_TGT + 2097152;        // f32  [B][64]
static constexpr size_t WS_SHP   = WS_TA + 4194304;         // bf16 [B][256] (padded shared)
static constexpr size_t WS_EO    = WS_SHP + 8388608;        // bf16 [B][8][128]
static constexpr size_t WS_GWB   = WS_EO + 33554432;        // bf16 [16][256]    (gate W, n-major, k pad 256)
static constexpr size_t WS_TW1B  = WS_GWB + 8192;           // bf16 [2][64][128] (tower1 W, n-major)
static constexpr size_t WS_TW2B  = WS_TW1B + 32768;         // bf16 [2][32][64]  (tower2 W, n-major)
// total = WS_TW2B + 8192 = 62,691,328 bytes of d_ws

// ---------------- k0: fold/transpose/bf16-cast weights + hist table ----------------
__launch_bounds__(256)
__global__ void k0_prep(const float* __restrict__ aW1, const float* __restrict__ aW2,
                        const float* __restrict__ eW1, const float* __restrict__ eW2,
                        const float* __restrict__ hist_E,
                        const float* __restrict__ gW, const float* __restrict__ tW1,
                        const float* __restrict__ tW2,
                        unsigned short* __restrict__ attnBt, unsigned short* __restrict__ aW2t,
                        float* __restrict__ A13,
                        unsigned short* __restrict__ eW1t, unsigned short* __restrict__ eW2t,
                        unsigned short* __restrict__ hist_b,
                        unsigned short* __restrict__ gWb, unsigned short* __restrict__ tW1b,
                        unsigned short* __restrict__ tW2b) {
  int tid = blockIdx.x * blockDim.x + threadIdx.x;
  int nth = gridDim.x * blockDim.x;
  // attnBt[n][k]: k<64 -> A2-A3 (h part), k>=64 -> A4 (t*h part)
  for (int i = tid; i < 64 * 128; i += nth) {
    int n = i >> 7, k = i & 127;
    float v = (k < 64) ? (aW1[(64 + k) * 64 + n] - aW1[(128 + k) * 64 + n])
                       : aW1[(128 + k) * 64 + n];
    attnBt[i] = f2bf(v);
  }
  // A13[k][n] = A1 + A3 (f32, for exact tA)
  for (int i = tid; i < 64 * 64; i += nth) {
    int k = i >> 6, n = i & 63;
    A13[i] = aW1[k * 64 + n] + aW1[(128 + k) * 64 + n];
  }
  // aW2t[n][k]
  for (int i = tid; i < 16 * 64; i += nth) {
    int n = i >> 6, k = i & 63;
    aW2t[i] = f2bf(aW2[k * 16 + n]);
  }
  // eW1t[e][n][k] (k<244 valid else 0)
  for (int i = tid; i < 8 * 256 * 256; i += nth) {
    int e = i >> 16, n = (i >> 8) & 255, k = i & 255;
    eW1t[i] = (k < 244) ? f2bf(eW1[(e * 244 + k) * 256 + n]) : (unsigned short)0;
  }
  // eW2t[e][n][k]
  for (int i = tid; i < 8 * 128 * 256; i += nth) {
    int e = i >> 15, n = (i >> 8) & 127, k = i & 255;
    eW2t[i] = f2bf(eW2[(e * 256 + k) * 128 + n]);
  }
  // gWb[n=t*8+e][k] (k pad 256)
  for (int i = tid; i < 16 * 256; i += nth) {
    int n = i >> 8, k = i & 255, t = n >> 3, e = n & 7;
    gWb[i] = (k < 244) ? f2bf(gW[(t * 244 + k) * 8 + e]) : (unsigned short)0;
  }
  // tW1b[t][n][k]
  for (int i = tid; i < 2 * 64 * 128; i += nth) {
    int t = i >> 13, n = (i >> 7) & 63, k = i & 127;
    tW1b[i] = f2bf(tW1[(t * 128 + k) * 64 + n]);
  }
  // tW2b[t][n][k]
  for (int i = tid; i < 2 * 32 * 64; i += nth) {
    int t = i >> 11, n = (i >> 6) & 31, k = i & 63;
    tW2b[i] = f2bf(tW2[(t * 64 + k) * 32 + n]);
  }
  // bf16 hist table (halves gather traffic in k2)
  for (int i = tid; i < 100001 * 64; i += nth) hist_b[i] = f2bf(hist_E[i]);
}

// ---------------- k1: t = i_emb @ Wproj ; tA = t @ (A1+A3) + ab1 ----------------
__launch_bounds__(256)
__global__ void k1_tgt(const int* __restrict__ item_id, const float* __restrict__ item_E,
                       const float* __restrict__ Wproj, const float* __restrict__ A13,
                       const float* __restrict__ ab1,
                       unsigned short* __restrict__ tgt, float* __restrict__ tA) {
  __shared__ float Wp[64 * 64], A13s[64 * 64], ab1s[64];
  __shared__ float ivb[4][64], tbuf[4][64];
  int tid = threadIdx.x, w = tid >> 6, lane = tid & 63;
  for (int i = tid; i < 4096; i += 256) { Wp[i] = Wproj[i]; A13s[i] = A13[i]; }
  if (tid < 64) ab1s[tid] = ab1[tid];
  __syncthreads();
  int b0 = blockIdx.x * 16;
  for (int it = 0; it < 4; ++it) {
    int b = b0 + w * 4 + it;
    int iid = item_id[b];
    ivb[w][lane] = item_E[(size_t)iid * 64 + lane];
    __syncthreads();
    float t = 0.f;
#pragma unroll 8
    for (int k = 0; k < 64; ++k) t += ivb[w][k] * Wp[k * 64 + lane];
    tbuf[w][lane] = t;
    __syncthreads();
    float ta = ab1s[lane];
#pragma unroll 8
    for (int k = 0; k < 64; ++k) ta += tbuf[w][k] * A13s[k * 64 + lane];
    tgt[(size_t)b * 64 + lane] = f2bf(t);
    tA[(size_t)b * 64 + lane] = ta;
  }
}

// ---------------- k3a: assemble shared (cols 0..179, pad 244..255) ----------------
__launch_bounds__(256)
__global__ void k3a_assemble(const int* __restrict__ user_id, const int* __restrict__ item_id,
                             const int* __restrict__ item_cat, const int* __restrict__ item_dur,
                             const float* __restrict__ user_dense, const float* __restrict__ item_dense,
                             const float* __restrict__ user_E, const float* __restrict__ item_E,
                             const float* __restrict__ cat_E, const float* __restrict__ dur_E,
                             unsigned short* __restrict__ shared_p) {
  int tid = threadIdx.x, w = tid >> 6, lane = tid & 63;
  int b = blockIdx.x * 4 + w;
  unsigned short* row = shared_p + (size_t)b * 256;
  row[lane]      = f2bf(user_E[(size_t)user_id[b] * 64 + lane]);
  row[64 + lane] = f2bf(item_E[(size_t)item_id[b] * 64 + lane]);
  if (lane < 16) row[128 + lane] = f2bf(cat_E[item_cat[b] * 16 + lane]);
  if (lane < 8)  row[144 + lane] = f2bf(dur_E[item_dur[b] * 8 + lane]);
  if (lane < 25) row[152 + lane] = f2bf(user_dense[b * 25 + lane]);
  if (lane < 3)  row[177 + lane] = f2bf(item_dense[b * 3 + lane]);
  if (lane < 12) row[244 + lane] = 0;
}

// ---------------- k2: fused DIN attention per batch element (M-fold, high occupancy) ----------------
__launch_bounds__(256, 5)
__global__ void k2_attn(const int* __restrict__ hist_seq, const unsigned short* __restrict__ hist_b,
                        const unsigned short* __restrict__ tgt, const float* __restrict__ tA,
                        const unsigned short* __restrict__ attnBt_g, const unsigned short* __restrict__ aW2t_g,
                        const float* __restrict__ ab2, const float* __restrict__ aW3,
                        unsigned short* __restrict__ shared_p) {
  __shared__ unsigned short sH1[208 * 64];   // layer1 output bf16 (swizzled); first 4096 transiently hold M
  __shared__ int   ids[208];
  __shared__ float tv[64], tAv[64];
  __shared__ float sSc[208];
  __shared__ float red[8];
  __shared__ float pbuf[512];
  int b = blockIdx.x;
  int tid = threadIdx.x, w = tid >> 6, lane = tid & 63;
  int lr = lane & 15, g = lane >> 4;

  if (tid < 208) ids[tid] = (tid < 200) ? hist_seq[(size_t)b * 200 + tid] : 0;
  if (tid < 64) tv[tid] = bf2f(tgt[(size_t)b * 64 + tid]);
  else if (tid < 128) tAv[tid - 64] = tA[(size_t)b * 64 + (tid - 64)];

  // layer-2 B fragments straight from global (L2-resident)
  bfrag b2fr[2];
#pragma unroll
  for (int kk = 0; kk < 2; ++kk)
    b2fr[kk] = *(const bfrag*)(aW2t_g + lr * 64 + kk * 32 + g * 8);
  float ab2v = ab2[lr];
  float aW3v = aW3[lr];
  __syncthreads();   // tv ready

  // cooperative M[n][k] = A23[n][k] + t[k]*A4[n][k]  into sH1[0:4096] (row stride 64, swizzled)
  {
    int n = tid >> 2, k0 = (tid & 3) * 16;
    const unsigned short* rowp = attnBt_g + n * 128;
    unsigned short a23[16], a4[16], mo[16];
    *(uint4*)(a23)     = *(const uint4*)(rowp + k0);
    *(uint4*)(a23 + 8) = *(const uint4*)(rowp + k0 + 8);
    *(uint4*)(a4)      = *(const uint4*)(rowp + 64 + k0);
    *(uint4*)(a4 + 8)  = *(const uint4*)(rowp + 64 + k0 + 8);
#pragma unroll
    for (int i = 0; i < 16; ++i)
      mo[i] = f2bf(bf2f(a23[i]) + tv[k0 + i] * bf2f(a4[i]));
    *(uint4*)(sH1 + n * 64 + SWZ(n, k0))     = *(uint4*)(mo);
    *(uint4*)(sH1 + n * 64 + SWZ(n, k0 + 8)) = *(uint4*)(mo + 8);
  }
  __syncthreads();   // M ready
  bfrag bfr[4][2];
#pragma unroll
  for (int nt = 0; nt < 4; ++nt)
#pragma unroll
    for (int kk = 0; kk < 2; ++kk) {
      int n = nt * 16 + lr;
      bfr[nt][kk] = *(const bfrag*)(sH1 + n * 64 + SWZ(n, kk * 32 + g * 8));
    }
  __syncthreads();   // all waves have M in regs; sH1 free for layer-1 output

  // layer 1: (208x64) @ (64x64) with per-batch folded M
  for (int mt = w; mt < 13; mt += 4) {
    int m = mt * 16 + lr;
    const unsigned short* hrow = hist_b + (size_t)ids[m] * 64;
    bfrag h0 = *(const bfrag*)(hrow + g * 8);          // k in [0,32)
    bfrag h1 = *(const bfrag*)(hrow + 32 + g * 8);     // k in [32,64)
    f32x4 acc[4] = {{0.f,0.f,0.f,0.f},{0.f,0.f,0.f,0.f},{0.f,0.f,0.f,0.f},{0.f,0.f,0.f,0.f}};
#pragma unroll
    for (int nt = 0; nt < 4; ++nt) {
      acc[nt] = __builtin_amdgcn_mfma_f32_16x16x32_bf16(h0, bfr[nt][0], acc[nt], 0, 0, 0);
      acc[nt] = __builtin_amdgcn_mfma_f32_16x16x32_bf16(h1, bfr[nt][1], acc[nt], 0, 0, 0);
    }
#pragma unroll
    for (int nt = 0; nt < 4; ++nt) {
      int n = nt * 16 + lr;
      float ta = tAv[n];
#pragma unroll
      for (int r = 0; r < 4; ++r) {
        float v = fmaxf(acc[nt][r] + ta, 0.f);
        int mm = mt * 16 + g * 4 + r;
        sH1[mm * 64 + SWZ(mm, n)] = f2bf(v);
      }
    }
  }
  __syncthreads();

  // layer 2: (208x64)@(64x16), + layer 3 dot via shuffle
  for (int mt = w; mt < 13; mt += 4) {
    f32x4 acc = {0.f, 0.f, 0.f, 0.f};
    int m = mt * 16 + lr;
#pragma unroll
    for (int kk = 0; kk < 2; ++kk) {
      int k0 = kk * 32 + g * 8;
      bfrag a = *(const bfrag*)(sH1 + m * 64 + SWZ(m, k0));
      acc = __builtin_amdgcn_mfma_f32_16x16x32_bf16(a, b2fr[kk], acc, 0, 0, 0);
    }
    float sc[4];
#pragma unroll
    for (int r = 0; r < 4; ++r) sc[r] = fmaxf(acc[r] + ab2v, 0.f) * aW3v;
#pragma unroll
    for (int d = 1; d < 16; d <<= 1)
#pragma unroll
      for (int r = 0; r < 4; ++r) sc[r] += __shfl_xor(sc[r], d);
    if (lr == 0) {
      int mr = mt * 16 + g * 4;
      sSc[mr] = sc[0]; sSc[mr + 1] = sc[1]; sSc[mr + 2] = sc[2]; sSc[mr + 3] = sc[3];
    }
  }
  __syncthreads();

  // masked softmax
  bool valid = false; float sc0 = 0.f;
  if (tid < 200 && ids[tid] != 0) { valid = true; sc0 = sSc[tid]; }
  float v = valid ? sc0 : -3.0e38f;
#pragma unroll
  for (int d = 1; d < 64; d <<= 1) v = fmaxf(v, __shfl_xor(v, d));
  if (lane == 0) red[w] = v;
  __syncthreads();
  float mx = fmaxf(fmaxf(red[0], red[1]), fmaxf(red[2], red[3]));
  float p = valid ? __expf(sc0 - mx) : 0.f;
  float s = p;
#pragma unroll
  for (int d = 1; d < 64; d <<= 1) s += __shfl_xor(s, d);
  if (lane == 0) red[4 + w] = s;
  if (tid < 208) sSc[tid] = p;
  __syncthreads();
  float denom = red[4] + red[5] + red[6] + red[7] + 1e-30f;

  // pooled: re-gather h (L2-warm) weighted by attn; u32 loads, 2 rows per wave-pass
  {
    int hp = lane >> 5, hl = lane & 31;
    float a0 = 0.f, a1 = 0.f;
    for (int i = 0; i < 25; ++i) {
      int l = w * 50 + hp * 25 + i;
      unsigned hv = *(const unsigned*)(hist_b + (size_t)ids[l] * 64 + 2 * hl);
      float pw = sSc[l];
      a0 += pw * bfLo(hv);
      a1 += pw * bfHi(hv);
    }
    pbuf[(w * 2 + hp) * 64 + 2 * hl]     = a0;
    pbuf[(w * 2 + hp) * 64 + 2 * hl + 1] = a1;
  }
  __syncthreads();
  if (tid < 64) {
    float tot = 0.f;
#pragma unroll
    for (int c = 0; c < 8; ++c) tot += pbuf[c * 64 + tid];
    shared_p[(size_t)b * 256 + 180 + tid] = f2bf(tot / denom);
  }
}

// ---------------- k3b: experts (64-row tile x one expert per block) ----------------
__launch_bounds__(256, 2)
__global__ void k3b_experts(const unsigned short* __restrict__ shared_p,
                            const unsigned short* __restrict__ eW1t, const unsigned short* __restrict__ eW2t,
                            const float* __restrict__ eb1, const float* __restrict__ eb2,
                            unsigned short* __restrict__ eo_ws) {
  __shared__ unsigned short sX[64 * 256];   // X tile then reused as H1 tile (swizzled)
  __shared__ unsigned short sW[256 * 64];   // weight K-chunk, n-major (swizzled)
  int tid = threadIdx.x, w = tid >> 6, lane = tid & 63;
  int e = blockIdx.x & 7;
  int b0 = (blockIdx.x >> 3) * 64;
  int lr = lane & 15, g = lane >> 4;

  for (int j = tid; j < 2048; j += 256) {
    int r = j >> 5, ke = (j & 31) * 8;
    uint4 v = *(const uint4*)(shared_p + (size_t)(b0 + r) * 256 + ke);
    *(uint4*)(sX + r * 256 + SWZ(r, ke)) = v;
  }
  f32x4 acc[16];
#pragma unroll
  for (int i = 0; i < 16; ++i) acc[i] = (f32x4){0.f, 0.f, 0.f, 0.f};
  const unsigned short* w1 = eW1t + (size_t)e * 256 * 256;
  for (int c = 0; c < 4; ++c) {
    __syncthreads();
    for (int j = tid; j < 2048; j += 256) {
      int n = j >> 3, ke = (j & 7) * 8;
      uint4 v = *(const uint4*)(w1 + n * 256 + c * 64 + ke);
      *(uint4*)(sW + n * 64 + SWZ(n, ke)) = v;
    }
    __syncthreads();
    int m = w * 16 + lr;
#pragma unroll
    for (int kk = 0; kk < 2; ++kk) {
      int kabs = c * 64 + kk * 32 + g * 8;
      bfrag a = *(const bfrag*)(sX + m * 256 + SWZ(m, kabs));
      int kloc = kk * 32 + g * 8;
#pragma unroll
      for (int nt = 0; nt < 16; ++nt) {
        int n = nt * 16 + lr;
        bfrag bb = *(const bfrag*)(sW + n * 64 + SWZ(n, kloc));
        acc[nt] = __builtin_amdgcn_mfma_f32_16x16x32_bf16(a, bb, acc[nt], 0, 0, 0);
      }
    }
  }
  __syncthreads();
  // h1 = relu(acc + eb1) -> reuse sX
#pragma unroll
  for (int nt = 0; nt < 16; ++nt) {
    int n = nt * 16 + lr;
    float bb = eb1[e * 256 + n];
#pragma unroll
    for (int r = 0; r < 4; ++r) {
      float vv = fmaxf(acc[nt][r] + bb, 0.f);
      int mm = w * 16 + g * 4 + r;
      sX[mm * 256 + SWZ(mm, n)] = f2bf(vv);
    }
  }
  f32x4 acc2[8];
#pragma unroll
  for (int i = 0; i < 8; ++i) acc2[i] = (f32x4){0.f, 0.f, 0.f, 0.f};
  const unsigned short* w2 = eW2t + (size_t)e * 128 * 256;
  for (int c = 0; c < 4; ++c) {
    __syncthreads();
    for (int j = tid; j < 1024; j += 256) {
      int n = j >> 3, ke = (j & 7) * 8;
      uint4 v = *(const uint4*)(w2 + n * 256 + c * 64 + ke);
      *(uint4*)(sW + n * 64 + SWZ(n, ke)) = v;
    }
    __syncthreads();
    int m = w * 16 + lr;
#pragma unroll
    for (int kk = 0; kk < 2; ++kk) {
      int kabs = c * 64 + kk * 32 + g * 8;
      bfrag a = *(const bfrag*)(sX + m * 256 + SWZ(m, kabs));
      int kloc = kk * 32 + g * 8;
#pragma unroll
      for (int nt = 0; nt < 8; ++nt) {
        int n = nt * 16 + lr;
        bfrag bb = *(const bfrag*)(sW + n * 64 + SWZ(n, kloc));
        acc2[nt] = __builtin_amdgcn_mfma_f32_16x16x32_bf16(a, bb, acc2[nt], 0, 0, 0);
      }
    }
  }
#pragma unroll
  for (int nt = 0; nt < 8; ++nt) {
    int n = nt * 16 + lr;
    float bb = eb2[e * 128 + n];
#pragma unroll
    for (int r = 0; r < 4; ++r) {
      float vv = fmaxf(acc2[nt][r] + bb, 0.f);
      int mm = w * 16 + g * 4 + r;
      eo_ws[((size_t)(b0 + mm) * 8 + e) * 128 + n] = f2bf(vv);
    }
  }
}

// ---------------- k4: gates + mixture + towers + sigmoid (MFMA tail) ----------------
// 512 blocks x 32 rows. LDS ~26.5KB. Weights read from L2 (bf16, n-major).
__launch_bounds__(256, 3)
__global__ void k4_tail(const unsigned short* __restrict__ shared_p, const unsigned short* __restrict__ eo_ws,
                        const unsigned short* __restrict__ gWb, const float* __restrict__ gb,
                        const unsigned short* __restrict__ tW1b, const float* __restrict__ tb1,
                        const unsigned short* __restrict__ tW2b, const float* __restrict__ tb2,
                        const float* __restrict__ tW3, const float* __restrict__ tb3,
                        float* __restrict__ out) {
  __shared__ float sGL[32 * 17];            // gate logits -> gates (padded)
  __shared__ unsigned short sTi[2 * 32 * 128]; // ti bf16 (swizzled) 16KB
  __shared__ unsigned short sX1[2 * 32 * 64];  // x1 bf16 (swizzled) 8KB
  int tid = threadIdx.x, w = tid >> 6, lane = tid & 63;
  int lr = lane & 15, g = lane >> 4;
  int b0 = blockIdx.x * 32;

  // ---- Phase A: gate logits via MFMA (32x16, K=256); waves 0,1 ----
  if (w < 2) {
    int m = b0 + w * 16 + lr;
    f32x4 acc = {0.f, 0.f, 0.f, 0.f};
#pragma unroll
    for (int kk = 0; kk < 8; ++kk) {
      bfrag a = *(const bfrag*)(shared_p + (size_t)m * 256 + kk * 32 + g * 8);
      bfrag bb = *(const bfrag*)(gWb + lr * 256 + kk * 32 + g * 8);
      acc = __builtin_amdgcn_mfma_f32_16x16x32_bf16(a, bb, acc, 0, 0, 0);
    }
    float gbv = gb[lr];
#pragma unroll
    for (int r = 0; r < 4; ++r)
      sGL[(w * 16 + g * 4 + r) * 17 + lr] = acc[r] + gbv;
  }
  __syncthreads();

  // ---- softmax over 8 experts per (row, task) ----
  if (tid < 64) {
    int row = tid >> 1, t = tid & 1;
    float* p = sGL + row * 17 + t * 8;
    float mx = -3e38f;
#pragma unroll
    for (int e = 0; e < 8; ++e) mx = fmaxf(mx, p[e]);
    float sum = 0.f; float pe[8];
#pragma unroll
    for (int e = 0; e < 8; ++e) { pe[e] = __expf(p[e] - mx); sum += pe[e]; }
    float inv = 1.f / sum;
#pragma unroll
    for (int e = 0; e < 8; ++e) p[e] = pe[e] * inv;
  }
  __syncthreads();

  // ---- Phase B: mixture ti[t][row][o] = sum_e gate * eo ; 8 threads/row ----
  {
    int row = tid >> 3, q = tid & 7, t = q >> 2, o0 = (q & 3) * 32;
    const float* gp = sGL + row * 17 + t * 8;
    float accL[16], accH[16];
#pragma unroll
    for (int j = 0; j < 16; ++j) { accL[j] = 0.f; accH[j] = 0.f; }
    const unsigned short* base = eo_ws + ((size_t)(b0 + row) * 8) * 128 + o0;
#pragma unroll
    for (int e = 0; e < 8; ++e) {
      float ge = gp[e];
      const unsigned short* p = base + e * 128;
#pragma unroll
      for (int c = 0; c < 4; ++c) {
        uint4 v = *(const uint4*)(p + c * 8);
        const unsigned* u = (const unsigned*)&v;
#pragma unroll
        for (int j = 0; j < 4; ++j) {
          accL[c * 4 + j] += ge * bfLo(u[j]);
          accH[c * 4 + j] += ge * bfHi(u[j]);
        }
      }
    }
    unsigned short ob[32];
#pragma unroll
    for (int j = 0; j < 16; ++j) {
      ob[2 * j]     = f2bf(accL[j]);
      ob[2 * j + 1] = f2bf(accH[j]);
    }
#pragma unroll
    for (int c = 0; c < 4; ++c)
      *(uint4*)(sTi + t * 4096 + row * 128 + SWZ(row, o0 + c * 8)) = *(const uint4*)(ob + c * 8);
  }
  __syncthreads();

  // ---- Phase C: tower1 via MFMA; wave w -> (t = w>>1, mt = w&1); 32x64 K=128 ----
  int t = w >> 1, mt = w & 1;
  {
    f32x4 acc[4] = {{0.f,0.f,0.f,0.f},{0.f,0.f,0.f,0.f},{0.f,0.f,0.f,0.f},{0.f,0.f,0.f,0.f}};
    int ml = mt * 16 + lr;
#pragma unroll
    for (int kk = 0; kk < 4; ++kk) {
      bfrag a = *(const bfrag*)(sTi + t * 4096 + ml * 128 + SWZ(ml, kk * 32 + g * 8));
#pragma unroll
      for (int nt = 0; nt < 4; ++nt) {
        bfrag bb = *(const bfrag*)(tW1b + t * 8192 + (nt * 16 + lr) * 128 + kk * 32 + g * 8);
        acc[nt] = __builtin_amdgcn_mfma_f32_16x16x32_bf16(a, bb, acc[nt], 0, 0, 0);
      }
    }
#pragma unroll
    for (int nt = 0; nt < 4; ++nt) {
      int n = nt * 16 + lr;
      float bias = tb1[t * 64 + n];
#pragma unroll
      for (int r = 0; r < 4; ++r) {
        float x = fmaxf(acc[nt][r] + bias, 0.f);
        int row = mt * 16 + g * 4 + r;
        sX1[t * 2048 + row * 64 + SWZ(row, n)] = f2bf(x);
      }
    }
  }
  __syncthreads();

  // ---- Phase D: tower2 MFMA (32x32 K=64) + tower3 dot + sigmoid ----
  {
    f32x4 acc[2] = {{0.f,0.f,0.f,0.f},{0.f,0.f,0.f,0.f}};
    int ml = mt * 16 + lr;
#pragma unroll
    for (int kk = 0; kk < 2; ++kk) {
      bfrag a = *(const bfrag*)(sX1 + t * 2048 + ml * 64 + SWZ(ml, kk * 32 + g * 8));
#pragma unroll
      for (int nt = 0; nt < 2; ++nt) {
        bfrag bb = *(const bfrag*)(tW2b + t * 2048 + (nt * 16 + lr) * 64 + kk * 32 + g * 8);
        acc[nt] = __builtin_amdgcn_mfma_f32_16x16x32_bf16(a, bb, acc[nt], 0, 0, 0);
      }
    }
    float part[4] = {0.f, 0.f, 0.f, 0.f};
#pragma unroll
    for (int nt = 0; nt < 2; ++nt) {
      int n = nt * 16 + lr;
      float bias = tb2[t * 32 + n];
      float w3 = tW3[t * 32 + n];
#pragma unroll
      for (int r = 0; r < 4; ++r)
        part[r] += fmaxf(acc[nt][r] + bias, 0.f) * w3;
    }
#pragma unroll
    for (int d = 1; d < 16; d <<= 1)
#pragma unroll
      for (int r = 0; r < 4; ++r) part[r] += __shfl_xor(part[r], d);
    if (lr == 0) {
      float b3 = tb3[t];
#pragma unroll
      for (int r = 0; r < 4; ++r) {
        float logit = part[r] + b3;
        out[(size_t)t * 16384 + b0 + mt * 16 + g * 4 + r] = 1.f / (1.f + __expf(-logit));
      }
    }
  }
}

// ---------------- launcher ----------------
extern "C" void kernel_launch(void* const* d_in, const int* in_sizes, int n_in,
                              void* d_out, int out_size, void* d_ws, size_t ws_size,
                              hipStream_t stream) {
  const int*   user_id    = (const int*)  d_in[0];
  const int*   item_id    = (const int*)  d_in[1];
  const int*   item_cat   = (const int*)  d_in[2];
  const int*   item_dur   = (const int*)  d_in[3];
  const float* user_dense = (const float*)d_in[4];
  const float* item_dense = (const float*)d_in[5];
  const int*   hist_seq   = (const int*)  d_in[6];
  const float* user_E     = (const float*)d_in[7];
  const float* item_E     = (const float*)d_in[8];
  const float* cat_E      = (const float*)d_in[9];
  const float* dur_E      = (const float*)d_in[10];
  const float* hist_E     = (const float*)d_in[11];
  const float* Wproj      = (const float*)d_in[12];
  const float* aW1        = (const float*)d_in[13];
  const float* ab1        = (const float*)d_in[14];
  const float* aW2        = (const float*)d_in[15];
  const float* ab2        = (const float*)d_in[16];
  const float* aW3        = (const float*)d_in[17];
  // d_in[18] = ab3: cancels in softmax, unused
  const float* eW1        = (const float*)d_in[19];
  const float* eb1        = (const float*)d_in[20];
  const float* eW2        = (const float*)d_in[21];
  const float* eb2        = (const float*)d_in[22];
  const float* gW         = (const float*)d_in[23];
  const float* gb         = (const float*)d_in[24];
  const float* tW1        = (const float*)d_in[25];
  const float* tb1        = (const float*)d_in[26];
  const float* tW2        = (const float*)d_in[27];
  const float* tb2        = (const float*)d_in[28];
  const float* tW3        = (const float*)d_in[29];
  const float* tb3        = (const float*)d_in[30];
  float* out = (float*)d_out;
  char* ws = (char*)d_ws;

  unsigned short* attnBt  = (unsigned short*)(ws + WS_ATTNB);
  unsigned short* aW2t    = (unsigned short*)(ws + WS_AW2T);
  float*          A13     = (float*)         (ws + WS_A13);
  unsigned short* eW1t    = (unsigned short*)(ws + WS_EW1T);
  unsigned short* eW2t    = (unsigned short*)(ws + WS_EW2T);
  unsigned short* hist_b  = (unsigned short*)(ws + WS_HISTB);
  unsigned short* tgt     = (unsigned short*)(ws + WS_TGT);
  float*          tA      = (float*)         (ws + WS_TA);
  unsigned short* shared_p= (unsigned short*)(ws + WS_SHP);
  unsigned short* eo_ws   = (unsigned short*)(ws + WS_EO);
  unsigned short* gWb     = (unsigned short*)(ws + WS_GWB);
  unsigned short* tW1b    = (unsigned short*)(ws + WS_TW1B);
  unsigned short* tW2b    = (unsigned short*)(ws + WS_TW2B);

  k0_prep<<<2048, 256, 0, stream>>>(aW1, aW2, eW1, eW2, hist_E, gW, tW1, tW2,
                                    attnBt, aW2t, A13, eW1t, eW2t, hist_b,
                                    gWb, tW1b, tW2b);
  k1_tgt<<<1024, 256, 0, stream>>>(item_id, item_E, Wproj, A13, ab1, tgt, tA);
  k3a_assemble<<<4096, 256, 0, stream>>>(user_id, item_id, item_cat, item_dur,
                                         user_dense, item_dense, user_E, item_E,
                                         cat_E, dur_E, shared_p);
  k2_attn<<<16384, 256, 0, stream>>>(hist_seq, hist_b, tgt, tA, attnBt, aW2t,
                                     ab2, aW3, shared_p);
  k3b_experts<<<2048, 256, 0, stream>>>(shared_p, eW1t, eW2t, eb1, eb2, eo_ws);
  k4_tail<<<512, 256, 0, stream>>>(shared_p, eo_ws, gWb, gb, tW1b, tb1, tW2b, tb2,
                                   tW3, tb3, out);
}